// Round 3
// baseline (8026.578 us; speedup 1.0000x reference)
//
#include <hip/hip_runtime.h>
#include <math.h>

// Problem constants
#define BB 64
#define SS 80
#define TT 20
#define FF 4096
#define HH 256
#define VV 32000

typedef __attribute__((ext_vector_type(8))) short bf16x8;
typedef __attribute__((ext_vector_type(4))) float f32x4;

__device__ __forceinline__ float fsig(float x){ return 1.f/(1.f+__expf(-x)); }
__device__ __forceinline__ float ftanh(float x){
    float xc = fminf(fmaxf(x,-15.f),15.f);
    float e = __expf(2.f*xc);
    return (e-1.f)/(e+1.f);
}
__device__ __forceinline__ unsigned int f2b(float x){
    unsigned int u = __float_as_uint(x);
    return (u + 0x7fffu + ((u>>16)&1u)) >> 16;
}
__device__ __forceinline__ float blo(unsigned int u){ return __uint_as_float(u<<16); }
__device__ __forceinline__ float bhi(unsigned int u){ return __uint_as_float(u & 0xffff0000u); }

// ---------------------------------------------------------------------------
// Device-scope grid barrier (monotonic counter; cnt zeroed before each launch)
// ---------------------------------------------------------------------------
__device__ __forceinline__ void gridbar(unsigned* cnt, unsigned nblk, unsigned* bi){
    __syncthreads();
    if (threadIdx.x == 0){
        (*bi)++;
        unsigned target = nblk * (*bi);
        __threadfence();   // release my block's writes (agent scope)
        __hip_atomic_fetch_add(cnt, 1u, __ATOMIC_ACQ_REL, __HIP_MEMORY_SCOPE_AGENT);
        while (__hip_atomic_load(cnt, __ATOMIC_ACQUIRE, __HIP_MEMORY_SCOPE_AGENT) < target)
            __builtin_amdgcn_s_sleep(1);
    }
    __syncthreads();
    __threadfence();       // acquire others' writes (invalidate L1)
}

// ---------------------------------------------------------------------------
// prep: packed-bf16 recurrence weights, M3, bias sums, gathers, W_out -> bf16
// pk layout: pk[k*512 + j] = bf16(W[j][k]) | bf16(W[j+512][k])<<16,  j in [0,512)
// ---------------------------------------------------------------------------
__global__ __launch_bounds__(256) void prep_kernel(
    const float* __restrict__ eWhh0, const float* __restrict__ eWih1, const float* __restrict__ eWhh1,
    const float* __restrict__ dWih0, const float* __restrict__ dWhh0, const float* __restrict__ dWih1,
    const float* __restrict__ dWhh1, const float* __restrict__ attWc,
    const float* __restrict__ cov_w, const float* __restrict__ cov_b,
    const float* __restrict__ e_bih0, const float* __restrict__ e_bhh0,
    const float* __restrict__ e_bih1, const float* __restrict__ e_bhh1,
    const float* __restrict__ d_bih0, const float* __restrict__ d_bhh0,
    const float* __restrict__ d_bih1, const float* __restrict__ d_bhh1,
    const int*   __restrict__ captions, const float* __restrict__ W_out,
    unsigned int* pkWhh0e, unsigned int* pkWih1e, unsigned int* pkWhh1e, unsigned int* pkWx0d,
    unsigned int* pkWhh0d, unsigned int* pkWih1d, unsigned int* pkWhh1d,
    float* M3, float* attcb,
    float* b0e, float* b1e, float* b0d, float* b1d, int* g2, int* g3,
    unsigned short* Wob)
{
    int blk = blockIdx.x, tid = threadIdx.x;
    if (blk < 896){
        int mat = blk >> 7, tl = blk & 127;
        const float* src; int stride, coff; unsigned int* dst;
        switch(mat){
            case 0: src=eWhh0; stride=256; coff=0;   dst=pkWhh0e; break;
            case 1: src=eWih1; stride=256; coff=0;   dst=pkWih1e; break;
            case 2: src=eWhh1; stride=256; coff=0;   dst=pkWhh1e; break;
            case 3: src=dWih0; stride=512; coff=256; dst=pkWx0d;  break;  // ctx columns
            case 4: src=dWhh0; stride=256; coff=0;   dst=pkWhh0d; break;
            case 5: src=dWih1; stride=256; coff=0;   dst=pkWih1d; break;
            default:src=dWhh1; stride=256; coff=0;   dst=pkWhh1d; break;
        }
        int jt = tl >> 3, kt = tl & 7;       // 16 j-tiles x 8 k-tiles
        int j0 = jt*32, k0 = kt*32;
        __shared__ float t1[32][33], t2[32][33];
        int r = tid >> 5, c = tid & 31;
        #pragma unroll
        for (int i=0;i<4;i++){
            int row = r + i*8;
            t1[row][c] = src[(size_t)(j0+row)*stride     + coff + k0 + c];
            t2[row][c] = src[(size_t)(j0+512+row)*stride + coff + k0 + c];
        }
        __syncthreads();
        #pragma unroll
        for (int i=0;i<4;i++){
            int row = r + i*8;               // k index within tile
            dst[(size_t)(k0+row)*512 + j0 + c] = f2b(t1[c][row]) | (f2b(t2[c][row])<<16);
        }
        return;
    }
    if (blk == 896){
        float m0=0.f,m1=0.f,m2=0.f,cb=0.f;
        for (int c=0;c<64;c++){
            float w = attWc[tid*64+c];
            m0 += w*cov_w[c*3+0]; m1 += w*cov_w[c*3+1]; m2 += w*cov_w[c*3+2];
            cb += w*cov_b[c];
        }
        M3[tid*3+0]=m0; M3[tid*3+1]=m1; M3[tid*3+2]=m2; attcb[tid]=cb;
        return;
    }
    if (blk == 897){
        for (int i=tid;i<1024;i+=256){
            b0e[i]=e_bih0[i]+e_bhh0[i]; b1e[i]=e_bih1[i]+e_bhh1[i];
            b0d[i]=d_bih0[i]+d_bhh0[i]; b1d[i]=d_bih1[i]+d_bhh1[i];
        }
        return;
    }
    if (blk == 898){
        for (int m=tid;m<SS*BB;m+=256) g2[m] = (m&63)*SS + (m>>6);
        return;
    }
    if (blk == 899){
        for (int m=tid;m<TT*BB;m+=256) g3[m] = captions[(m&63)*TT + (m>>6)];
        return;
    }
    // W_out -> bf16 (8.192M elements, 4000 blocks x 2048 els)
    {
        size_t idx = (size_t)(blk-900)*2048 + tid*8;
        float4 a  = *reinterpret_cast<const float4*>(W_out+idx);
        float4 b4 = *reinterpret_cast<const float4*>(W_out+idx+4);
        uint4 o;
        o.x = f2b(a.x)  | (f2b(a.y)<<16);
        o.y = f2b(a.z)  | (f2b(a.w)<<16);
        o.z = f2b(b4.x) | (f2b(b4.y)<<16);
        o.w = f2b(b4.z) | (f2b(b4.w)<<16);
        *reinterpret_cast<uint4*>(Wob+idx) = o;
    }
}

// ---------------------------------------------------------------------------
// Generic tiled fp32 GEMM: C = A[M,K] @ B[N,K]^T (+bias), A-row gather, split-K
// ---------------------------------------------------------------------------
template<int BM,int BN,int TM,int TN>
__global__ __launch_bounds__(256) void gemm_nt(int M,int N,int K,
    const float* __restrict__ A, int lda,
    const float* __restrict__ B, int ldb,
    float* __restrict__ C, int ldc,
    const float* __restrict__ bias,
    const int* __restrict__ gatherA,
    int Ksl, size_t Cslice)
{
    constexpr int BK=16;
    constexpr int TX=BN/TN, TY=BM/TM;
    static_assert(TX*TY==256, "256 threads");
    __shared__ float As[BK][BM+4];
    __shared__ float Bs[BK][BN+4];
    int tid = threadIdx.x;
    int tx = tid%TX, ty = tid/TX;
    int m0 = blockIdx.y*BM, n0 = blockIdx.x*BN;
    int kz = blockIdx.z;
    int kstart = kz*Ksl, kend = min(K, kstart+Ksl);
    C += (size_t)kz * Cslice;
    const float* bz = (kz==0) ? bias : nullptr;
    float acc[TM][TN] = {};
    int lr = tid>>2, lk = (tid&3)*4;
    for (int k0=kstart;k0<kend;k0+=BK){
        #pragma unroll
        for (int r=lr;r<BM;r+=64){
            int arow = gatherA ? gatherA[m0+r] : (m0+r);
            float4 v = *reinterpret_cast<const float4*>(A + (size_t)arow*lda + k0 + lk);
            As[lk+0][r]=v.x; As[lk+1][r]=v.y; As[lk+2][r]=v.z; As[lk+3][r]=v.w;
        }
        #pragma unroll
        for (int r=lr;r<BN;r+=64){
            float4 v = *reinterpret_cast<const float4*>(B + (size_t)(n0+r)*ldb + k0 + lk);
            Bs[lk+0][r]=v.x; Bs[lk+1][r]=v.y; Bs[lk+2][r]=v.z; Bs[lk+3][r]=v.w;
        }
        __syncthreads();
        #pragma unroll
        for (int k=0;k<BK;k++){
            float a[TM], bv[TN];
            #pragma unroll
            for (int i=0;i<TM;i++) a[i]=As[k][ty*TM+i];
            #pragma unroll
            for (int j=0;j<TN;j++) bv[j]=Bs[k][tx*TN+j];
            #pragma unroll
            for (int i=0;i<TM;i++)
                #pragma unroll
                for (int j=0;j<TN;j++) acc[i][j] += a[i]*bv[j];
        }
        __syncthreads();
    }
    #pragma unroll
    for (int i=0;i<TM;i++){
        size_t m = m0 + ty*TM + i;
        #pragma unroll
        for (int j=0;j<TN;j++){
            int n = n0 + tx*TN + j;
            C[m*ldc + n] = acc[i][j] + (bz ? bz[n] : 0.f);
        }
    }
}

// sum 4 split-K partials -> vp
__global__ __launch_bounds__(256) void vp_reduce(const float* __restrict__ part,
                                                 float* __restrict__ vp)
{
    size_t i = (size_t)blockIdx.x*256 + threadIdx.x;   // float4 index
    const float4* p = reinterpret_cast<const float4*>(part);
    float4 a = p[i], b = p[i+327680], c = p[i+655360], d = p[i+983040];
    a.x += b.x+c.x+d.x; a.y += b.y+c.y+d.y; a.z += b.z+c.z+d.z; a.w += b.w+c.w+d.w;
    reinterpret_cast<float4*>(vp)[i] = a;
}

// ---------------------------------------------------------------------------
// Persistent LSTM slice: block covers 4 batches (b0..b0+3) x 32 h (hc*32..),
// threads: b_l(2, each 2 batches) x kh(2, k-split) x gate(2) x h_l(32).
// Weights packed: Wpk[k*512 + j] = gate-pair (j, j+512) columns in bf16.
// shmem layout: xs[4][256] | hs[4][256] | zs[4][2][2][2][32]   (3072 floats)
// ---------------------------------------------------------------------------
#define ZIDX(bb,pr,gt,kk,hl) (((((bb)*2+(pr))*2+(gt))*2+(kk))*32+(hl))

__device__ __forceinline__ void lstm_persist(
    int tid, int b0, int hc,
    const float* __restrict__ xall,  // [64][256] or null
    const float* __restrict__ hall,  // [64][256]
    const unsigned* __restrict__ WxPk, const unsigned* __restrict__ WhPk,
    const float* __restrict__ bias,       // [1024] or null
    const float* __restrict__ baserows,   // [64][1024] or null
    float* __restrict__ cbuf, float* __restrict__ hout,
    float* __restrict__ extra, int extra_stride, float* sh)
{
    float* xs = sh;
    float* hs = sh + 1024;
    float* zs = sh + 2048;
    for (int i=tid; i<1024; i+=256){
        int bb = i>>8, k = i&255;
        hs[i] = hall[(size_t)(b0+bb)*256 + k];
        if (xall) xs[i] = xall[(size_t)(b0+bb)*256 + k];
    }
    __syncthreads();
    int b_l = tid>>7, kh = (tid>>6)&1, gate = (tid>>5)&1, h_l = tid&31;
    int j0 = gate*256 + hc*32 + h_l;
    float a0_0=0.f, a1_0=0.f, a0_1=0.f, a1_1=0.f;   // acc[pair][local batch]
    const unsigned* wh = WhPk + (size_t)(kh*128)*512 + j0;
    const float* h0 = hs + (b_l*2  )*256 + kh*128;
    const float* h1 = hs + (b_l*2+1)*256 + kh*128;
    if (WxPk){
        const unsigned* wx = WxPk + (size_t)(kh*128)*512 + j0;
        const float* x0 = xs + (b_l*2  )*256 + kh*128;
        const float* x1 = xs + (b_l*2+1)*256 + kh*128;
        #pragma unroll 8
        for (int k=0;k<128;k++){
            unsigned uw = wx[(size_t)k*512], uh = wh[(size_t)k*512];
            float wxl=blo(uw), wxh=bhi(uw), whl=blo(uh), whh=bhi(uh);
            float xv0=x0[k], hv0=h0[k], xv1=x1[k], hv1=h1[k];
            a0_0 += xv0*wxl + hv0*whl;  a1_0 += xv0*wxh + hv0*whh;
            a0_1 += xv1*wxl + hv1*whl;  a1_1 += xv1*wxh + hv1*whh;
        }
    } else {
        #pragma unroll 16
        for (int k=0;k<128;k++){
            unsigned uh = wh[(size_t)k*512];
            float whl=blo(uh), whh=bhi(uh);
            float hv0=h0[k], hv1=h1[k];
            a0_0 += hv0*whl;  a1_0 += hv0*whh;
            a0_1 += hv1*whl;  a1_1 += hv1*whh;
        }
    }
    zs[ZIDX(b_l*2  ,0,gate,kh,h_l)] = a0_0;
    zs[ZIDX(b_l*2  ,1,gate,kh,h_l)] = a1_0;
    zs[ZIDX(b_l*2+1,0,gate,kh,h_l)] = a0_1;
    zs[ZIDX(b_l*2+1,1,gate,kh,h_l)] = a1_1;
    __syncthreads();
    if (tid < 128){
        int pb = tid>>5, ph = tid&31;
        int bb = b0+pb, h = hc*32+ph, idx = bb*256 + h;
        float i_ = zs[ZIDX(pb,0,0,0,ph)] + zs[ZIDX(pb,0,0,1,ph)];
        float f_ = zs[ZIDX(pb,0,1,0,ph)] + zs[ZIDX(pb,0,1,1,ph)];
        float g_ = zs[ZIDX(pb,1,0,0,ph)] + zs[ZIDX(pb,1,0,1,ph)];
        float o_ = zs[ZIDX(pb,1,1,0,ph)] + zs[ZIDX(pb,1,1,1,ph)];
        int j = hc*32 + ph;
        if (bias){ i_ += bias[j]; f_ += bias[j+256]; g_ += bias[j+512]; o_ += bias[j+768]; }
        if (baserows){
            const float* br = baserows + (size_t)bb*1024;
            i_ += br[j]; f_ += br[j+256]; g_ += br[j+512]; o_ += br[j+768];
        }
        float cn = fsig(f_)*cbuf[idx] + fsig(i_)*ftanh(g_);
        cbuf[idx] = cn;
        float hn = fsig(o_)*ftanh(cn);
        hout[idx] = hn;
        if (extra) extra[(size_t)bb*extra_stride + h] = hn;
    }
}

// ---------------------------------------------------------------------------
// Persistent encoder: 256 blocks. 0-127: layer0 step t; 128-255: layer1 step t-1
// ---------------------------------------------------------------------------
__global__ __launch_bounds__(256, 2) void enc_persist(
    const float* __restrict__ zx0,
    const unsigned* __restrict__ pkWhh0e, const unsigned* __restrict__ pkWih1e,
    const unsigned* __restrict__ pkWhh1e, const float* __restrict__ b1e,
    float* h1buf, float* c1, float* h2buf, float* c2, float* enc_out,
    unsigned* bar_cnt)
{
    __shared__ float sh[3072];
    int blk = blockIdx.x;
    bool is0 = blk < 128;
    int lb = is0 ? blk : blk-128;
    int bc = lb>>3, hc = lb&7, b0 = bc*4;
    unsigned bi = 0;
    for (int t=0; t<=SS; ++t){
        if (is0){
            if (t < SS)
                lstm_persist(threadIdx.x, b0, hc, nullptr, h1buf + ((t+1)&1)*16384,
                             nullptr, pkWhh0e, nullptr, zx0 + (size_t)t*65536,
                             c1, h1buf + (t&1)*16384, nullptr, 0, sh);
        } else {
            if (t >= 1){
                int u = t-1;
                lstm_persist(threadIdx.x, b0, hc, h1buf + (u&1)*16384, h2buf + (u&1)*16384,
                             pkWih1e, pkWhh1e, b1e, nullptr,
                             c2, h2buf + ((u+1)&1)*16384, enc_out + (size_t)u*256, SS*256, sh);
            }
        }
        gridbar(bar_cnt, 256, &bi);
    }
}

// ---------------------------------------------------------------------------
// Attention body (block b, persistent) — shmem-carved scratch
// ---------------------------------------------------------------------------
__device__ __forceinline__ void attn_body(int b, int tid,
    const float* __restrict__ h2prev, const float* __restrict__ encp,
    const float* __restrict__ enco, const float* __restrict__ attWs,
    const float* __restrict__ att_v, const float* __restrict__ M3,
    const float* __restrict__ attcb, float* __restrict__ cov,
    float* __restrict__ ctx, float* sh)
{
    float* h2s   = sh;        // 256
    float* dps   = sh + 256;  // 256
    float* covs  = sh + 512;  // 82
    float* scs   = sh + 608;  // 80
    float* attns = sh + 704;  // 80
    h2s[tid] = h2prev[b*256 + tid];
    if (tid < 80) covs[tid+1] = cov[b*80 + tid];
    if (tid == 80) covs[0] = 0.f;
    if (tid == 81) covs[81] = 0.f;
    __syncthreads();
    {
        float acc = attcb[tid];
        const float4* wr = reinterpret_cast<const float4*>(attWs + (size_t)tid*256);
        #pragma unroll 8
        for (int kq=0;kq<64;kq++){
            float4 w4 = wr[kq];
            acc += h2s[kq*4]*w4.x + h2s[kq*4+1]*w4.y + h2s[kq*4+2]*w4.z + h2s[kq*4+3]*w4.w;
        }
        dps[tid] = acc;
    }
    __syncthreads();
    int wave = tid>>6, lane = tid&63;
    float va[4], dp4[4], m30[4], m31[4], m32[4];
    #pragma unroll
    for (int i=0;i<4;i++){
        int h = lane + i*64;
        va[i]=att_v[h]; dp4[i]=dps[h];
        m30[i]=M3[h*3+0]; m31[i]=M3[h*3+1]; m32[i]=M3[h*3+2];
    }
    for (int s = wave*20; s < wave*20 + 20; s++){
        float c0 = covs[s], c1v = covs[s+1], c2v = covs[s+2];
        float p = 0.f;
        #pragma unroll
        for (int i=0;i<4;i++){
            int h = lane + i*64;
            float e = encp[((size_t)b*80 + s)*256 + h] + dp4[i] + m30[i]*c0 + m31[i]*c1v + m32[i]*c2v;
            p += va[i]*ftanh(e);
        }
        #pragma unroll
        for (int off=32;off;off>>=1) p += __shfl_down(p, off);
        if (lane == 0) scs[s] = p;
    }
    __syncthreads();
    if (tid < 64){
        float a = scs[tid];
        float bsc = (tid < 16) ? scs[tid+64] : -3.4e38f;
        float mx = fmaxf(a, bsc);
        #pragma unroll
        for (int off=32;off;off>>=1) mx = fmaxf(mx, __shfl_xor(mx, off));
        float ea = __expf(a - mx);
        float eb = (tid < 16) ? __expf(bsc - mx) : 0.f;
        float sum = ea + eb;
        #pragma unroll
        for (int off=32;off;off>>=1) sum += __shfl_xor(sum, off);
        float inv = 1.f/sum;
        attns[tid] = ea*inv;
        if (tid < 16) attns[tid+64] = eb*inv;
    }
    __syncthreads();
    if (tid < 80) cov[b*80 + tid] = covs[tid+1] + attns[tid];
    float cacc = 0.f;
    for (int s=0;s<80;s++) cacc += attns[s]*enco[((size_t)b*80 + s)*256 + tid];
    ctx[b*256 + tid] = cacc;
}

// ---------------------------------------------------------------------------
// Persistent decoder: 128 blocks. Per t: [0-63: attn] bar [lstm0] bar [lstm1] bar
// ---------------------------------------------------------------------------
__global__ __launch_bounds__(256, 2) void dec_persist(
    const float* __restrict__ embproj,
    const unsigned* __restrict__ pkWx0d, const unsigned* __restrict__ pkWhh0d,
    const unsigned* __restrict__ pkWih1d, const unsigned* __restrict__ pkWhh1d,
    const float* __restrict__ b1d,
    const float* __restrict__ encproj, const float* __restrict__ enc_out,
    const float* __restrict__ attWs, const float* __restrict__ att_v,
    const float* __restrict__ M3, const float* __restrict__ attcb,
    const float* __restrict__ encH1, const float* __restrict__ encH2,
    float* h1dec, float* c1, float* c2, float* cov, float* ctx, float* h2all,
    unsigned* bar_cnt)
{
    __shared__ float sh[3072];
    int blk = blockIdx.x, tid = threadIdx.x;
    int bc = blk>>3, hc = blk&7, b0 = bc*4;
    unsigned bi = 0;
    for (int t=0; t<TT; ++t){
        const float* h2prev = t ? (h2all + (size_t)(t-1)*16384) : encH2;
        if (blk < 64)
            attn_body(blk, tid, h2prev, encproj, enc_out, attWs, att_v, M3, attcb,
                      cov, ctx, sh);
        gridbar(bar_cnt, 128, &bi);
        const float* h1in = t ? (h1dec + (size_t)((t-1)&1)*16384) : encH1;
        lstm_persist(tid, b0, hc, ctx, h1in, pkWx0d, pkWhh0d, nullptr,
                     embproj + (size_t)t*65536, c1, h1dec + (size_t)(t&1)*16384,
                     nullptr, 0, sh);
        gridbar(bar_cnt, 128, &bi);
        lstm_persist(tid, b0, hc, h1dec + (size_t)(t&1)*16384, h2prev,
                     pkWih1d, pkWhh1d, b1d, nullptr,
                     c2, h2all + (size_t)t*16384, nullptr, 0, sh);
        gridbar(bar_cnt, 128, &bi);
    }
}

// ---------------------------------------------------------------------------
// LayerNorm -> bf16 rows for the logits MFMA
// ---------------------------------------------------------------------------
__global__ __launch_bounds__(256) void ln_kernel(
    const float* __restrict__ h2all, const float* __restrict__ g,
    const float* __restrict__ be, unsigned short* __restrict__ normedb)
{
    int row = blockIdx.x;           // b*20 + t
    int b = row/TT, t = row%TT;
    int tid = threadIdx.x;
    __shared__ float red[4];
    float x = h2all[((size_t)t*64 + b)*256 + tid];
    float s = x;
    #pragma unroll
    for (int off=32;off;off>>=1) s += __shfl_down(s, off);
    if ((tid&63) == 0) red[tid>>6] = s;
    __syncthreads();
    float mean = (red[0]+red[1]+red[2]+red[3]) * (1.f/256.f);
    __syncthreads();
    float d = x - mean;
    float sq = d*d;
    #pragma unroll
    for (int off=32;off;off>>=1) sq += __shfl_down(sq, off);
    if ((tid&63) == 0) red[tid>>6] = sq;
    __syncthreads();
    float var = (red[0]+red[1]+red[2]+red[3]) * (1.f/256.f);
    float val = d*rsqrtf(var + 1e-5f)*g[tid] + be[tid];
    normedb[(size_t)row*256 + tid] = (unsigned short)f2b(val);
}

// ---------------------------------------------------------------------------
// Logits: bf16 MFMA, W-stationary. Block = 64 n-cols (4 waves x 16); loops all
// 80 m-tiles. W_out read ONCE from HBM; A (0.65 MB) stays L2-resident.
// ---------------------------------------------------------------------------
__global__ __launch_bounds__(256) void logits_mfma(
    const short* __restrict__ A, const short* __restrict__ Bw,
    const float* __restrict__ bias, float* __restrict__ out)
{
    int w = threadIdx.x >> 6, lane = threadIdx.x & 63;
    int n0 = blockIdx.x*64 + w*16;
    int row = lane & 15, kg = lane >> 4;
    bf16x8 bfr[8];
    const short* brow = Bw + (size_t)(n0 + row)*256 + kg*8;
    #pragma unroll
    for (int kk=0;kk<8;kk++) bfr[kk] = *reinterpret_cast<const bf16x8*>(brow + kk*32);
    float bv = bias[n0 + row];
    for (int mt=0; mt<80; ++mt){
        int m0 = mt*16;
        const short* arow = A + (size_t)(m0 + row)*256 + kg*8;
        f32x4 acc = {};
        #pragma unroll
        for (int kk=0;kk<8;kk++){
            bf16x8 a = *reinterpret_cast<const bf16x8*>(arow + kk*32);
            acc = __builtin_amdgcn_mfma_f32_16x16x32_bf16(a, bfr[kk], acc, 0, 0, 0);
        }
        #pragma unroll
        for (int r=0;r<4;r++){
            int m = m0 + kg*4 + r;
            out[(size_t)m*VV + n0 + row] = acc[r] + bv;
        }
    }
}

// ---------------------------------------------------------------------------
extern "C" void kernel_launch(void* const* d_in, const int* in_sizes, int n_in,
                              void* d_out, int out_size, void* d_ws, size_t ws_size,
                              hipStream_t stream)
{
    const float* video  = (const float*)d_in[0];
    const int*   caps   = (const int*)  d_in[1];
    const float* W_vp   = (const float*)d_in[2];
    const float* b_vp   = (const float*)d_in[3];
    const float* eWih0  = (const float*)d_in[4];
    const float* eWhh0  = (const float*)d_in[5];
    const float* e_bih0 = (const float*)d_in[6];
    const float* e_bhh0 = (const float*)d_in[7];
    const float* eWih1  = (const float*)d_in[8];
    const float* eWhh1  = (const float*)d_in[9];
    const float* e_bih1 = (const float*)d_in[10];
    const float* e_bhh1 = (const float*)d_in[11];
    const float* emb    = (const float*)d_in[12];
    const float* dWih0  = (const float*)d_in[13];
    const float* dWhh0  = (const float*)d_in[14];
    const float* d_bih0 = (const float*)d_in[15];
    const float* d_bhh0 = (const float*)d_in[16];
    const float* dWih1  = (const float*)d_in[17];
    const float* dWhh1  = (const float*)d_in[18];
    const float* d_bih1 = (const float*)d_in[19];
    const float* d_bhh1 = (const float*)d_in[20];
    const float* attWh  = (const float*)d_in[21];
    const float* attWs  = (const float*)d_in[22];
    const float* att_v  = (const float*)d_in[23];
    const float* attWc  = (const float*)d_in[24];
    const float* cov_w  = (const float*)d_in[25];
    const float* cov_b  = (const float*)d_in[26];
    const float* ln_g   = (const float*)d_in[27];
    const float* ln_b   = (const float*)d_in[28];
    const float* W_out  = (const float*)d_in[29];
    const float* b_out  = (const float*)d_in[30];
    float* out = (float*)d_out;

    float* W = (float*)d_ws;
    size_t o = 0;
    auto alloc = [&](size_t n){ size_t r = o; o += ((n + 63)/64)*64; return r; };

    // zero-initialized state region (contiguous, memset below)
    unsigned* bar_e = (unsigned*)(W + alloc(64));     // enc barrier counter
    unsigned* bar_d = (unsigned*)(W + alloc(64));     // dec barrier counter
    float* h1buf = W + alloc(2*64*256);
    float* h2buf = W + alloc(2*64*256);
    float* c1    = W + alloc(64*256);
    float* c2    = W + alloc(64*256);
    float* cov   = W + alloc(64*80);
    size_t state_bytes = o * sizeof(float);

    float* h1dec   = W + alloc(2*64*256);
    float* vp      = W + alloc((size_t)SS*BB*HH);       // [b][s][h] fp32
    float* zx0     = W + alloc((size_t)SS*BB*1024);     // [t][b][1024]; aliases vp_part
    float* vp_part = zx0;                               // 4 x (5120*256) split-K partials
    float* embproj = W + alloc((size_t)TT*BB*1024);     // [t][b][1024]
    float* enc_out = W + alloc((size_t)BB*SS*HH);       // [b][s][h]
    float* encproj = W + alloc((size_t)BB*SS*HH);       // [b][s][h]
    float* h2all   = W + alloc((size_t)TT*BB*HH);       // [t][b][h]
    float* ctx     = W + alloc((size_t)BB*HH);
    unsigned short* normedb = (unsigned short*)(W + alloc((size_t)BB*TT*HH/2));
    unsigned int* pkWhh0e = (unsigned int*)(W + alloc(256*512));
    unsigned int* pkWih1e = (unsigned int*)(W + alloc(256*512));
    unsigned int* pkWhh1e = (unsigned int*)(W + alloc(256*512));
    unsigned int* pkWx0d  = (unsigned int*)(W + alloc(256*512));
    unsigned int* pkWhh0d = (unsigned int*)(W + alloc(256*512));
    unsigned int* pkWih1d = (unsigned int*)(W + alloc(256*512));
    unsigned int* pkWhh1d = (unsigned int*)(W + alloc(256*512));
    float* M3      = W + alloc(256*3);
    float* attcb   = W + alloc(256);
    float* b0e     = W + alloc(1024);
    float* b1e     = W + alloc(1024);
    float* b0d     = W + alloc(1024);
    float* b1d     = W + alloc(1024);
    int*   g2      = (int*)(W + alloc(SS*BB));
    int*   g3      = (int*)(W + alloc(TT*BB));
    unsigned short* Wob = (unsigned short*)(W + alloc((size_t)VV*HH/2));
    (void)ws_size; (void)n_in; (void)in_sizes; (void)out_size;

    hipMemsetAsync(W, 0, state_bytes, stream);

    prep_kernel<<<4900, 256, 0, stream>>>(
        eWhh0, eWih1, eWhh1, dWih0, dWhh0, dWih1, dWhh1, attWc,
        cov_w, cov_b, e_bih0, e_bhh0, e_bih1, e_bhh1, d_bih0, d_bhh0, d_bih1, d_bhh1,
        caps, W_out,
        pkWhh0e, pkWih1e, pkWhh1e, pkWx0d, pkWhh0d, pkWih1d, pkWhh1d,
        M3, attcb, b0e, b1e, b0d, b1d, g2, g3, Wob);

    // vp = video @ W_vp^T + b_vp   (5120x256, K=4096) — split-K x4 partials
    gemm_nt<64,64,4,4><<<dim3(4,80,4), 256, 0, stream>>>(
        SS*BB, HH, FF, video, FF, W_vp, FF, vp_part, HH, b_vp, nullptr,
        1024, (size_t)SS*BB*HH);
    vp_reduce<<<1280, 256, 0, stream>>>(vp_part, vp);

    // zx0[t][b] = vp[b][t] @ eWih0^T + (bih0+bhh0)   (5120x1024, K=256)
    gemm_nt<64,64,4,4><<<dim3(16,80), 256, 0, stream>>>(
        SS*BB, 1024, HH, vp, HH, eWih0, HH, zx0, 1024, b0e, g2, HH, 0);

    // embproj[t][b] = emb[tok] @ dWih0[:, :256]^T + (bih0+bhh0)   (1280x1024, K=256)
    gemm_nt<64,64,4,4><<<dim3(16,20), 256, 0, stream>>>(
        TT*BB, 1024, HH, emb, HH, dWih0, 512, embproj, 1024, b0d, g3, HH, 0);

    // encoder scan — persistent, 81 grid barriers
    enc_persist<<<256, 256, 0, stream>>>(zx0, pkWhh0e, pkWih1e, pkWhh1e, b1e,
                                         h1buf, c1, h2buf, c2, enc_out, bar_e);

    // enc_proj = enc_out @ att_Wh^T   (5120x256, K=256)
    gemm_nt<64,64,4,4><<<dim3(4,80), 256, 0, stream>>>(
        SS*BB, HH, HH, enc_out, HH, attWh, HH, encproj, HH, nullptr, nullptr, HH, 0);

    const float* encH1 = h1buf + 16384;   // h1 after step 79 (parity 1)
    const float* encH2 = h2buf;           // h2 after step 79 (parity 0)

    // decoder scan — persistent, 60 grid barriers
    dec_persist<<<128, 256, 0, stream>>>(embproj, pkWx0d, pkWhh0d, pkWih1d, pkWhh1d,
                                         b1d, encproj, enc_out, attWs, att_v, M3, attcb,
                                         encH1, encH2, h1dec, c1, c2, cov, ctx, h2all,
                                         bar_d);

    ln_kernel<<<BB*TT, 256, 0, stream>>>(h2all, ln_g, ln_b, normedb);

    // logits = normed @ W_out^T + b_out   (1280 x 32000, K=256)
    logits_mfma<<<VV/64, 256, 0, stream>>>(
        (const short*)normedb, (const short*)Wob, b_out, out);
}

// Round 4
// 2113.741 us; speedup vs baseline: 3.7973x; 3.7973x over previous
//
#include <hip/hip_runtime.h>
#include <math.h>

// Problem constants
#define BB 64
#define SS 80
#define TT 20
#define FF 4096
#define HH 256
#define VV 32000

typedef __attribute__((ext_vector_type(8))) short bf16x8;
typedef __attribute__((ext_vector_type(4))) float f32x4;

__device__ __forceinline__ float fsig(float x){ return 1.f/(1.f+__expf(-x)); }
__device__ __forceinline__ float ftanh(float x){
    float xc = fminf(fmaxf(x,-15.f),15.f);
    float e = __expf(2.f*xc);
    return (e-1.f)/(e+1.f);
}
__device__ __forceinline__ unsigned int f2b(float x){
    unsigned int u = __float_as_uint(x);
    return (u + 0x7fffu + ((u>>16)&1u)) >> 16;
}
// acc += dot2(bf16pair w, bf16pair h)  -- CDNA v_dot2_f32_bf16
__device__ __forceinline__ float dot2bf(unsigned w, unsigned hp, float acc){
    float r;
    asm("v_dot2_f32_bf16 %0, %1, %2, %3" : "=v"(r) : "v"(w), "v"(hp), "v"(acc));
    return r;
}

// ---------------------------------------------------------------------------
// prep: k-pair-packed bf16 weights pk[k2*Nj + j] = bf16 W[j][2k2] | bf16 W[j][2k2+1]<<16
// matrices 0..6 (Nj=1024), 7 = attWs (Nj=256); plus M3, bias sums, W_out->bf16
// ---------------------------------------------------------------------------
__global__ __launch_bounds__(256) void prep_kernel(
    const float* __restrict__ eWhh0, const float* __restrict__ eWih1, const float* __restrict__ eWhh1,
    const float* __restrict__ dWih0, const float* __restrict__ dWhh0, const float* __restrict__ dWih1,
    const float* __restrict__ dWhh1, const float* __restrict__ attWs, const float* __restrict__ attWc,
    const float* __restrict__ cov_w, const float* __restrict__ cov_b,
    const float* __restrict__ e_bih0, const float* __restrict__ e_bhh0,
    const float* __restrict__ e_bih1, const float* __restrict__ e_bhh1,
    const float* __restrict__ d_bih0, const float* __restrict__ d_bhh0,
    const float* __restrict__ d_bih1, const float* __restrict__ d_bhh1,
    const float* __restrict__ W_out,
    unsigned* pkWhh0e, unsigned* pkWih1e, unsigned* pkWhh1e, unsigned* pkWx0d,
    unsigned* pkWhh0d, unsigned* pkWih1d, unsigned* pkWhh1d, unsigned* pkWs,
    float* M3, float* attcb,
    float* b0e, float* b1e, float* b0d, float* b1d,
    unsigned short* Wob)
{
    int blk = blockIdx.x, tid = threadIdx.x;
    if (blk < 1856){
        const float* src; int stride, coff, Nj, j0, k0; unsigned* dst;
        if (blk < 1792){
            int mat = blk >> 8, tl = blk & 255;
            switch(mat){
                case 0: src=eWhh0; stride=256; coff=0;   dst=pkWhh0e; break;
                case 1: src=eWih1; stride=256; coff=0;   dst=pkWih1e; break;
                case 2: src=eWhh1; stride=256; coff=0;   dst=pkWhh1e; break;
                case 3: src=dWih0; stride=512; coff=256; dst=pkWx0d;  break;  // ctx cols
                case 4: src=dWhh0; stride=256; coff=0;   dst=pkWhh0d; break;
                case 5: src=dWih1; stride=256; coff=0;   dst=pkWih1d; break;
                default:src=dWhh1; stride=256; coff=0;   dst=pkWhh1d; break;
            }
            Nj = 1024; j0 = (tl>>3)*32; k0 = (tl&7)*32;
        } else {
            int tl = blk - 1792;
            src=attWs; stride=256; coff=0; dst=pkWs;
            Nj = 256; j0 = (tl>>3)*32; k0 = (tl&7)*32;
        }
        __shared__ float t1[32][33];
        int r = tid >> 5, c = tid & 31;
        #pragma unroll
        for (int i=0;i<4;i++)
            t1[r+i*8][c] = src[(size_t)(j0+r+i*8)*stride + coff + k0 + c];
        __syncthreads();
        int k2l = tid >> 5, j = tid & 31;
        #pragma unroll
        for (int i=0;i<2;i++){
            int kq = k2l + i*8;
            dst[(size_t)(k0/2 + kq)*Nj + j0 + j] =
                f2b(t1[j][2*kq]) | (f2b(t1[j][2*kq+1])<<16);
        }
        return;
    }
    if (blk == 1856){
        float m0=0.f,m1=0.f,m2=0.f,cb=0.f;
        for (int c=0;c<64;c++){
            float w = attWc[tid*64+c];
            m0 += w*cov_w[c*3+0]; m1 += w*cov_w[c*3+1]; m2 += w*cov_w[c*3+2];
            cb += w*cov_b[c];
        }
        M3[tid*3+0]=m0; M3[tid*3+1]=m1; M3[tid*3+2]=m2; attcb[tid]=cb;
        return;
    }
    if (blk == 1857){
        for (int i=tid;i<1024;i+=256){
            b0e[i]=e_bih0[i]+e_bhh0[i]; b1e[i]=e_bih1[i]+e_bhh1[i];
            b0d[i]=d_bih0[i]+d_bhh0[i]; b1d[i]=d_bih1[i]+d_bhh1[i];
        }
        return;
    }
    // W_out -> bf16 (8.192M elems, 4000 blocks x 2048)
    {
        size_t idx = (size_t)(blk-1858)*2048 + tid*8;
        float4 a  = *reinterpret_cast<const float4*>(W_out+idx);
        float4 b4 = *reinterpret_cast<const float4*>(W_out+idx+4);
        uint4 o;
        o.x = f2b(a.x)  | (f2b(a.y)<<16);
        o.y = f2b(a.z)  | (f2b(a.w)<<16);
        o.z = f2b(b4.x) | (f2b(b4.y)<<16);
        o.w = f2b(b4.z) | (f2b(b4.w)<<16);
        *reinterpret_cast<uint4*>(Wob+idx) = o;
    }
}

// ---------------------------------------------------------------------------
// Generic tiled fp32 GEMM: C = A[M,K] @ B[N,K]^T (+bias), A-row gather, split-K
// ---------------------------------------------------------------------------
template<int BM,int BN,int TM,int TN>
__global__ __launch_bounds__(256) void gemm_nt(int M,int N,int K,
    const float* __restrict__ A, int lda,
    const float* __restrict__ B, int ldb,
    float* __restrict__ C, int ldc,
    const float* __restrict__ bias,
    const int* __restrict__ gatherA,
    int Ksl, size_t Cslice)
{
    constexpr int BK=16;
    constexpr int TX=BN/TN, TY=BM/TM;
    static_assert(TX*TY==256, "256 threads");
    __shared__ float As[BK][BM+4];
    __shared__ float Bs[BK][BN+4];
    int tid = threadIdx.x;
    int tx = tid%TX, ty = tid/TX;
    int m0 = blockIdx.y*BM, n0 = blockIdx.x*BN;
    int kz = blockIdx.z;
    int kstart = kz*Ksl, kend = min(K, kstart+Ksl);
    C += (size_t)kz * Cslice;
    const float* bz = (kz==0) ? bias : nullptr;
    float acc[TM][TN] = {};
    int lr = tid>>2, lk = (tid&3)*4;
    for (int k0=kstart;k0<kend;k0+=BK){
        #pragma unroll
        for (int r=lr;r<BM;r+=64){
            int arow = gatherA ? gatherA[m0+r] : (m0+r);
            float4 v = *reinterpret_cast<const float4*>(A + (size_t)arow*lda + k0 + lk);
            As[lk+0][r]=v.x; As[lk+1][r]=v.y; As[lk+2][r]=v.z; As[lk+3][r]=v.w;
        }
        #pragma unroll
        for (int r=lr;r<BN;r+=64){
            float4 v = *reinterpret_cast<const float4*>(B + (size_t)(n0+r)*ldb + k0 + lk);
            Bs[lk+0][r]=v.x; Bs[lk+1][r]=v.y; Bs[lk+2][r]=v.z; Bs[lk+3][r]=v.w;
        }
        __syncthreads();
        #pragma unroll
        for (int k=0;k<BK;k++){
            float a[TM], bv[TN];
            #pragma unroll
            for (int i=0;i<TM;i++) a[i]=As[k][ty*TM+i];
            #pragma unroll
            for (int j=0;j<TN;j++) bv[j]=Bs[k][tx*TN+j];
            #pragma unroll
            for (int i=0;i<TM;i++)
                #pragma unroll
                for (int j=0;j<TN;j++) acc[i][j] += a[i]*bv[j];
        }
        __syncthreads();
    }
    #pragma unroll
    for (int i=0;i<TM;i++){
        size_t m = m0 + ty*TM + i;
        #pragma unroll
        for (int j=0;j<TN;j++){
            int n = n0 + tx*TN + j;
            C[m*ldc + n] = acc[i][j] + (bz ? bz[n] : 0.f);
        }
    }
}

// sum 8 split-K partials -> vp
__global__ __launch_bounds__(256) void vp_reduce(const float* __restrict__ part,
                                                 float* __restrict__ vp)
{
    size_t i = (size_t)blockIdx.x*256 + threadIdx.x;   // float4 index
    const float4* p = reinterpret_cast<const float4*>(part);
    float4 a = p[i];
    #pragma unroll
    for (int s=1;s<8;s++){
        float4 b = p[i + (size_t)s*327680];
        a.x+=b.x; a.y+=b.y; a.z+=b.z; a.w+=b.w;
    }
    reinterpret_cast<float4*>(vp)[i] = a;
}

// ---------------------------------------------------------------------------
// dot phase: thread computes 4 outputs (j = jq*4..+3) over ITERS k-pairs
// w layout [128 k2][1024 j] bf16-pairs; h: LDS bf16 pairs
// ---------------------------------------------------------------------------
template<int ITERS>
__device__ __forceinline__ void dot_phase(const unsigned* __restrict__ wbase,
    const unsigned* __restrict__ hu, int k2base, int jq, float* __restrict__ zrow)
{
    float a0=0.f,a1=0.f,a2=0.f,a3=0.f;
    const uint4* wp = (const uint4*)(wbase + (size_t)k2base*1024 + jq*4);
    #pragma unroll 8
    for (int kk=0; kk<ITERS; ++kk){
        uint4 w = wp[(size_t)kk*256];
        unsigned hp = hu[k2base+kk];
        a0=dot2bf(w.x,hp,a0); a1=dot2bf(w.y,hp,a1);
        a2=dot2bf(w.z,hp,a2); a3=dot2bf(w.w,hp,a3);
    }
    zrow[jq*4+0]=a0; zrow[jq*4+1]=a1; zrow[jq*4+2]=a2; zrow[jq*4+3]=a3;
}

// ---------------------------------------------------------------------------
// Encoder scan: one block per batch row, 1024 threads, state in LDS, no barriers
// ---------------------------------------------------------------------------
__global__ __launch_bounds__(1024) void enc_scan(
    const float* __restrict__ zx0,       // [(b*80+t)*1024] incl bias
    const unsigned* __restrict__ wh0, const unsigned* __restrict__ wi1,
    const unsigned* __restrict__ wh1, const float* __restrict__ b1e,
    float* __restrict__ enc_out,         // [(b*80+t)*256]
    float* __restrict__ encfC, unsigned short* __restrict__ encfH)
{
    int b = blockIdx.x, tid = threadIdx.x;
    __shared__ unsigned short h1b[256], h2b[256];
    __shared__ float c1s[256], c2s[256];
    __shared__ float zb[4][1024];
    int h = tid & 255;
    float bz0=0.f,bz1=0.f,bz2=0.f,bz3=0.f;
    if (tid < 256){
        h1b[tid]=0; h2b[tid]=0; c1s[tid]=0.f; c2s[tid]=0.f;
        bz0=b1e[tid]; bz1=b1e[tid+256]; bz2=b1e[tid+512]; bz3=b1e[tid+768];
    }
    int ks  = tid >> 8;        // 0..3 (phase A k-quarter)
    int jq  = tid & 255;       // output quad
    int m1  = tid >> 9;        // 0..1 (phase C matrix)
    int ks1 = (tid >> 8) & 1;  // 0..1 (phase C k-half)
    const unsigned* h1u = (const unsigned*)h1b;
    const unsigned* h2u = (const unsigned*)h2b;
    __syncthreads();
    for (int t=0; t<SS; ++t){
        float zx0v=0.f,zx1v=0.f,zx2v=0.f,zx3v=0.f;
        if (tid < 256){
            const float* zr = zx0 + ((size_t)b*SS + t)*1024;
            zx0v=zr[h]; zx1v=zr[h+256]; zx2v=zr[h+512]; zx3v=zr[h+768];
        }
        // layer0: z = h1 @ Whh0^T (x-part precomputed in zx)
        dot_phase<32>(wh0, h1u, ks*32, jq, &zb[ks][0]);
        __syncthreads();
        if (tid < 256){
            float i_ = zx0v+zb[0][h]+zb[1][h]+zb[2][h]+zb[3][h];
            float f_ = zx1v+zb[0][h+256]+zb[1][h+256]+zb[2][h+256]+zb[3][h+256];
            float g_ = zx2v+zb[0][h+512]+zb[1][h+512]+zb[2][h+512]+zb[3][h+512];
            float o_ = zx3v+zb[0][h+768]+zb[1][h+768]+zb[2][h+768]+zb[3][h+768];
            float cn = fsig(f_)*c1s[h] + fsig(i_)*ftanh(g_);
            c1s[h] = cn;
            h1b[h] = (unsigned short)f2b(fsig(o_)*ftanh(cn));
        }
        __syncthreads();
        // layer1: z = h1 @ Wih1^T + h2 @ Whh1^T
        dot_phase<64>(m1 ? wh1 : wi1, m1 ? h2u : h1u, ks1*64, jq, &zb[m1*2+ks1][0]);
        __syncthreads();
        if (tid < 256){
            float i_ = bz0+zb[0][h]+zb[1][h]+zb[2][h]+zb[3][h];
            float f_ = bz1+zb[0][h+256]+zb[1][h+256]+zb[2][h+256]+zb[3][h+256];
            float g_ = bz2+zb[0][h+512]+zb[1][h+512]+zb[2][h+512]+zb[3][h+512];
            float o_ = bz3+zb[0][h+768]+zb[1][h+768]+zb[2][h+768]+zb[3][h+768];
            float cn = fsig(f_)*c2s[h] + fsig(i_)*ftanh(g_);
            c2s[h] = cn;
            float hn = fsig(o_)*ftanh(cn);
            h2b[h] = (unsigned short)f2b(hn);
            enc_out[((size_t)b*SS + t)*256 + h] = hn;
        }
        __syncthreads();
    }
    if (tid < 256){
        encfH[b*512 + tid]       = h1b[tid];
        encfH[b*512 + 256 + tid] = h2b[tid];
        encfC[b*512 + tid]       = c1s[tid];
        encfC[b*512 + 256 + tid] = c2s[tid];
    }
}

// ---------------------------------------------------------------------------
// Decoder scan: one block per batch row, 1024 threads; attn+lstm0+lstm1+LN fused
// ---------------------------------------------------------------------------
__global__ __launch_bounds__(1024) void dec_scan(
    const float* __restrict__ embproj,   // [(b*20+t)*1024] incl bias
    const unsigned* __restrict__ wx0, const unsigned* __restrict__ whh0,
    const unsigned* __restrict__ wih1, const unsigned* __restrict__ whh1,
    const unsigned* __restrict__ pkWs,   // [128 k2][256 h]
    const float* __restrict__ b1d,
    const float* __restrict__ encp, const float* __restrict__ enco,
    const float* __restrict__ att_v, const float* __restrict__ M3,
    const float* __restrict__ attcb,
    const float* __restrict__ ln_g, const float* __restrict__ ln_b,
    const float* __restrict__ encfC, const unsigned short* __restrict__ encfH,
    unsigned short* __restrict__ normedb)
{
    int b = blockIdx.x, tid = threadIdx.x;
    __shared__ unsigned short h1b[256], h2b[256], ctxb[256];
    __shared__ float c1s[256], c2s[256];
    __shared__ float zb[4][1024];
    __shared__ float covs[82], scs[80], attns[80], dps[256];
    __shared__ float red[16];
    int h = tid & 255;
    float bz0=0.f,bz1=0.f,bz2=0.f,bz3=0.f, gg=0.f, bb2=0.f;
    if (tid < 256){
        h1b[tid] = encfH[b*512 + tid];
        h2b[tid] = encfH[b*512 + 256 + tid];
        c1s[tid] = encfC[b*512 + tid];
        c2s[tid] = encfC[b*512 + 256 + tid];
        bz0=b1d[tid]; bz1=b1d[tid+256]; bz2=b1d[tid+512]; bz3=b1d[tid+768];
        gg=ln_g[tid]; bb2=ln_b[tid];
    }
    if (tid < 82) covs[tid] = 0.f;
    int wv = tid >> 6, lane = tid & 63;
    float va[4], m30[4], m31[4], m32[4];
    #pragma unroll
    for (int i=0;i<4;i++){
        int hh = lane + i*64;
        va[i]=att_v[hh]; m30[i]=M3[hh*3]; m31[i]=M3[hh*3+1]; m32[i]=M3[hh*3+2];
    }
    int q   = tid >> 8;        // 0..3
    int jq  = tid & 255;
    int m1  = tid >> 9;
    int ks1 = (tid >> 8) & 1;
    const unsigned* h1u = (const unsigned*)h1b;
    const unsigned* h2u = (const unsigned*)h2b;
    const unsigned* cxu = (const unsigned*)ctxb;
    __syncthreads();
    for (int t=0; t<TT; ++t){
        // ---- attention ----
        {   // dec_proj partials (bf16 dot2, k-split 4)
            float acc = 0.f;
            const unsigned* wp = pkWs + (size_t)(q*32)*256 + h;
            #pragma unroll 8
            for (int kk=0; kk<32; ++kk)
                acc = dot2bf(wp[(size_t)kk*256], h2u[q*32+kk], acc);
            zb[q][h] = acc;
        }
        __syncthreads();
        if (tid < 256) dps[tid] = attcb[tid] + zb[0][tid]+zb[1][tid]+zb[2][tid]+zb[3][tid];
        __syncthreads();
        for (int s = wv*5; s < wv*5+5; ++s){
            float c0=covs[s], c1v=covs[s+1], c2v=covs[s+2];
            float p = 0.f;
            #pragma unroll
            for (int i=0;i<4;i++){
                int hh = lane + i*64;
                float e = encp[((size_t)b*80+s)*256+hh] + dps[hh]
                        + m30[i]*c0 + m31[i]*c1v + m32[i]*c2v;
                p += va[i]*ftanh(e);
            }
            #pragma unroll
            for (int off=32;off;off>>=1) p += __shfl_down(p, off);
            if (lane == 0) scs[s] = p;
        }
        __syncthreads();
        if (tid < 64){
            float a = scs[tid];
            float bsc = (tid < 16) ? scs[tid+64] : -3.4e38f;
            float mx = fmaxf(a, bsc);
            #pragma unroll
            for (int off=32;off;off>>=1) mx = fmaxf(mx, __shfl_xor(mx, off));
            float ea = __expf(a - mx);
            float eb = (tid < 16) ? __expf(bsc - mx) : 0.f;
            float sum = ea + eb;
            #pragma unroll
            for (int off=32;off;off>>=1) sum += __shfl_xor(sum, off);
            float inv = 1.f/sum;
            attns[tid] = ea*inv;
            if (tid < 16) attns[tid+64] = eb*inv;
        }
        __syncthreads();
        if (tid < 80) covs[tid+1] += attns[tid];
        {   // ctx partials (s-split 4)
            float acc = 0.f;
            for (int s=q*20; s<q*20+20; ++s)
                acc += attns[s]*enco[((size_t)b*80+s)*256 + h];
            zb[q][h] = acc;
        }
        __syncthreads();
        if (tid < 256)
            ctxb[h] = (unsigned short)f2b(zb[0][h]+zb[1][h]+zb[2][h]+zb[3][h]);
        float ep0=0.f,ep1=0.f,ep2=0.f,ep3=0.f;
        if (tid < 256){
            const float* er = embproj + ((size_t)b*TT + t)*1024;
            ep0=er[h]; ep1=er[h+256]; ep2=er[h+512]; ep3=er[h+768];
        }
        __syncthreads();
        // ---- lstm0: x = ctx (wx0), h = h1 (whh0) ----
        dot_phase<64>(m1 ? whh0 : wx0, m1 ? h1u : cxu, ks1*64, jq, &zb[m1*2+ks1][0]);
        __syncthreads();
        if (tid < 256){
            float i_ = ep0+zb[0][h]+zb[1][h]+zb[2][h]+zb[3][h];
            float f_ = ep1+zb[0][h+256]+zb[1][h+256]+zb[2][h+256]+zb[3][h+256];
            float g_ = ep2+zb[0][h+512]+zb[1][h+512]+zb[2][h+512]+zb[3][h+512];
            float o_ = ep3+zb[0][h+768]+zb[1][h+768]+zb[2][h+768]+zb[3][h+768];
            float cn = fsig(f_)*c1s[h] + fsig(i_)*ftanh(g_);
            c1s[h] = cn;
            h1b[h] = (unsigned short)f2b(fsig(o_)*ftanh(cn));
        }
        __syncthreads();
        // ---- lstm1: x = h1 (wih1), h = h2 (whh1) ----
        dot_phase<64>(m1 ? whh1 : wih1, m1 ? h2u : h1u, ks1*64, jq, &zb[m1*2+ks1][0]);
        __syncthreads();
        float hn = 0.f;
        if (tid < 256){
            float i_ = bz0+zb[0][h]+zb[1][h]+zb[2][h]+zb[3][h];
            float f_ = bz1+zb[0][h+256]+zb[1][h+256]+zb[2][h+256]+zb[3][h+256];
            float g_ = bz2+zb[0][h+512]+zb[1][h+512]+zb[2][h+512]+zb[3][h+512];
            float o_ = bz3+zb[0][h+768]+zb[1][h+768]+zb[2][h+768]+zb[3][h+768];
            float cn = fsig(f_)*c2s[h] + fsig(i_)*ftanh(g_);
            c2s[h] = cn;
            hn = fsig(o_)*ftanh(cn);
            h2b[h] = (unsigned short)f2b(hn);
        }
        // fused LayerNorm over h2 (256 values held by threads 0..255)
        float s1 = hn;
        #pragma unroll
        for (int off=32;off;off>>=1) s1 += __shfl_xor(s1, off);
        if (lane == 0) red[wv] = s1;
        __syncthreads();
        float mean = (red[0]+red[1]+red[2]+red[3]) * (1.f/256.f);
        __syncthreads();
        float d = (tid < 256) ? (hn - mean) : 0.f;
        float s2 = d*d;
        #pragma unroll
        for (int off=32;off;off>>=1) s2 += __shfl_xor(s2, off);
        if (lane == 0) red[wv] = s2;
        __syncthreads();
        float var = (red[0]+red[1]+red[2]+red[3]) * (1.f/256.f);
        if (tid < 256)
            normedb[((size_t)b*TT + t)*256 + h] =
                (unsigned short)f2b(d*rsqrtf(var + 1e-5f)*gg + bb2);
        __syncthreads();
    }
}

// ---------------------------------------------------------------------------
// Logits: bf16 MFMA, W-stationary. Block = 64 n-cols; loops all 80 m-tiles.
// ---------------------------------------------------------------------------
__global__ __launch_bounds__(256) void logits_mfma(
    const short* __restrict__ A, const short* __restrict__ Bw,
    const float* __restrict__ bias, float* __restrict__ out)
{
    int w = threadIdx.x >> 6, lane = threadIdx.x & 63;
    int n0 = blockIdx.x*64 + w*16;
    int row = lane & 15, kg = lane >> 4;
    bf16x8 bfr[8];
    const short* brow = Bw + (size_t)(n0 + row)*256 + kg*8;
    #pragma unroll
    for (int kk=0;kk<8;kk++) bfr[kk] = *reinterpret_cast<const bf16x8*>(brow + kk*32);
    float bv = bias[n0 + row];
    for (int mt=0; mt<80; ++mt){
        int m0 = mt*16;
        const short* arow = A + (size_t)(m0 + row)*256 + kg*8;
        f32x4 acc = {};
        #pragma unroll
        for (int kk=0;kk<8;kk++){
            bf16x8 a = *reinterpret_cast<const bf16x8*>(arow + kk*32);
            acc = __builtin_amdgcn_mfma_f32_16x16x32_bf16(a, bfr[kk], acc, 0, 0, 0);
        }
        #pragma unroll
        for (int r=0;r<4;r++){
            int m = m0 + kg*4 + r;
            out[(size_t)m*VV + n0 + row] = acc[r] + bv;
        }
    }
}

// ---------------------------------------------------------------------------
extern "C" void kernel_launch(void* const* d_in, const int* in_sizes, int n_in,
                              void* d_out, int out_size, void* d_ws, size_t ws_size,
                              hipStream_t stream)
{
    const float* video  = (const float*)d_in[0];
    const int*   caps   = (const int*)  d_in[1];
    const float* W_vp   = (const float*)d_in[2];
    const float* b_vp   = (const float*)d_in[3];
    const float* eWih0  = (const float*)d_in[4];
    const float* eWhh0  = (const float*)d_in[5];
    const float* e_bih0 = (const float*)d_in[6];
    const float* e_bhh0 = (const float*)d_in[7];
    const float* eWih1  = (const float*)d_in[8];
    const float* eWhh1  = (const float*)d_in[9];
    const float* e_bih1 = (const float*)d_in[10];
    const float* e_bhh1 = (const float*)d_in[11];
    const float* emb    = (const float*)d_in[12];
    const float* dWih0  = (const float*)d_in[13];
    const float* dWhh0  = (const float*)d_in[14];
    const float* d_bih0 = (const float*)d_in[15];
    const float* d_bhh0 = (const float*)d_in[16];
    const float* dWih1  = (const float*)d_in[17];
    const float* dWhh1  = (const float*)d_in[18];
    const float* d_bih1 = (const float*)d_in[19];
    const float* d_bhh1 = (const float*)d_in[20];
    const float* attWh  = (const float*)d_in[21];
    const float* attWs  = (const float*)d_in[22];
    const float* att_v  = (const float*)d_in[23];
    const float* attWc  = (const float*)d_in[24];
    const float* cov_w  = (const float*)d_in[25];
    const float* cov_b  = (const float*)d_in[26];
    const float* ln_g   = (const float*)d_in[27];
    const float* ln_b   = (const float*)d_in[28];
    const float* W_out  = (const float*)d_in[29];
    const float* b_out  = (const float*)d_in[30];
    float* out = (float*)d_out;

    float* W = (float*)d_ws;
    size_t o = 0;
    auto alloc = [&](size_t n){ size_t r = o; o += ((n + 63)/64)*64; return r; };

    // big shared region R: vp_part (8 x 5120x256) overlaps {zx0, embproj}
    float* R       = W + alloc((size_t)8*SS*BB*HH);     // 10,485,760 floats
    float* vp_part = R;
    float* zx0     = R;                                  // [(b*80+t)*1024]
    float* embproj = R + (size_t)SS*BB*1024;             // [(b*20+t)*1024]
    float* vp      = W + alloc((size_t)SS*BB*HH);        // [b*80+t][256]
    float* enc_out = W + alloc((size_t)BB*SS*HH);        // [(b*80+t)*256]
    float* encproj = W + alloc((size_t)BB*SS*HH);
    unsigned short* normedb = (unsigned short*)(W + alloc((size_t)BB*TT*HH/2));
    float* encfC   = W + alloc(BB*512);
    unsigned short* encfH = (unsigned short*)(W + alloc(BB*256));
    unsigned* pkWhh0e = (unsigned*)(W + alloc(128*1024));
    unsigned* pkWih1e = (unsigned*)(W + alloc(128*1024));
    unsigned* pkWhh1e = (unsigned*)(W + alloc(128*1024));
    unsigned* pkWx0d  = (unsigned*)(W + alloc(128*1024));
    unsigned* pkWhh0d = (unsigned*)(W + alloc(128*1024));
    unsigned* pkWih1d = (unsigned*)(W + alloc(128*1024));
    unsigned* pkWhh1d = (unsigned*)(W + alloc(128*1024));
    unsigned* pkWs    = (unsigned*)(W + alloc(128*256));
    float* M3      = W + alloc(768);
    float* attcb   = W + alloc(256);
    float* b0e     = W + alloc(1024);
    float* b1e     = W + alloc(1024);
    float* b0d     = W + alloc(1024);
    float* b1d     = W + alloc(1024);
    unsigned short* Wob = (unsigned short*)(W + alloc((size_t)VV*HH/2));
    (void)ws_size; (void)n_in; (void)in_sizes; (void)out_size;

    prep_kernel<<<5858, 256, 0, stream>>>(
        eWhh0, eWih1, eWhh1, dWih0, dWhh0, dWih1, dWhh1, attWs, attWc,
        cov_w, cov_b, e_bih0, e_bhh0, e_bih1, e_bhh1, d_bih0, d_bhh0, d_bih1, d_bhh1,
        W_out,
        pkWhh0e, pkWih1e, pkWhh1e, pkWx0d, pkWhh0d, pkWih1d, pkWhh1d, pkWs,
        M3, attcb, b0e, b1e, b0d, b1d, Wob);

    // vp = video @ W_vp^T + b_vp  (5120x256, K=4096) split-K x8
    gemm_nt<64,64,4,4><<<dim3(4,80,8), 256, 0, stream>>>(
        SS*BB, HH, FF, video, FF, W_vp, FF, vp_part, HH, b_vp, nullptr,
        512, (size_t)SS*BB*HH);
    vp_reduce<<<1280, 256, 0, stream>>>(vp_part, vp);

    // zx0[b*80+t] = vp @ eWih0^T + (bih0+bhh0)   (5120x1024, K=256)
    gemm_nt<64,64,4,4><<<dim3(16,80), 256, 0, stream>>>(
        SS*BB, 1024, HH, vp, HH, eWih0, HH, zx0, 1024, b0e, nullptr, HH, 0);

    // embproj[b*20+t] = emb[cap] @ dWih0[:, :256]^T + (bih0+bhh0)  (1280x1024, K=256)
    gemm_nt<64,64,4,4><<<dim3(16,20), 256, 0, stream>>>(
        TT*BB, 1024, HH, emb, HH, dWih0, 512, embproj, 1024, b0d, caps, HH, 0);

    // encoder scan: 64 per-batch blocks, no inter-block sync
    enc_scan<<<64, 1024, 0, stream>>>(zx0, pkWhh0e, pkWih1e, pkWhh1e, b1e,
                                      enc_out, encfC, encfH);

    // enc_proj = enc_out @ att_Wh^T  (5120x256, K=256)
    gemm_nt<64,64,4,4><<<dim3(4,80), 256, 0, stream>>>(
        SS*BB, HH, HH, enc_out, HH, attWh, HH, encproj, HH, nullptr, nullptr, HH, 0);

    // decoder scan: 64 per-batch blocks (attn + lstm0 + lstm1 + LN fused)
    dec_scan<<<64, 1024, 0, stream>>>(embproj, pkWx0d, pkWhh0d, pkWih1d, pkWhh1d,
                                      pkWs, b1d, encproj, enc_out, att_v, M3, attcb,
                                      ln_g, ln_b, encfC, encfH, normedb);

    // logits = normed @ W_out^T + b_out  (1280 x 32000, K=256)
    logits_mfma<<<VV/64, 256, 0, stream>>>(
        (const short*)normedb, (const short*)Wob, b_out, out);
}

// Round 5
// 1538.376 us; speedup vs baseline: 5.2176x; 1.3740x over previous
//
#include <hip/hip_runtime.h>
#include <math.h>

// Problem constants
#define BB 64
#define SS 80
#define TT 20
#define FF 4096
#define HH 256
#define VV 32000

typedef __attribute__((ext_vector_type(8))) short bf16x8;
typedef __attribute__((ext_vector_type(4))) float f32x4;

__device__ __forceinline__ float fsig(float x){ return 1.f/(1.f+__expf(-x)); }
__device__ __forceinline__ float ftanh(float x){
    float xc = fminf(fmaxf(x,-15.f),15.f);
    float e = __expf(2.f*xc);
    return (e-1.f)/(e+1.f);
}
__device__ __forceinline__ unsigned int f2b(float x){
    unsigned int u = __float_as_uint(x);
    return (u + 0x7fffu + ((u>>16)&1u)) >> 16;
}
// acc += dot2(bf16pair w, bf16pair h)  -- CDNA v_dot2_f32_bf16
__device__ __forceinline__ float dot2bf(unsigned w, unsigned hp, float acc){
    float r;
    asm("v_dot2_f32_bf16 %0, %1, %2, %3" : "=v"(r) : "v"(w), "v"(hp), "v"(acc));
    return r;
}

// ---------------------------------------------------------------------------
// prep: k-pair-packed bf16 weights pk[k2*Nj + j] = bf16 W[j][2k2] | bf16 W[j][2k2+1]<<16
// matrices 0..6 (Nj=1024), 7 = attWs (Nj=256); M3, bias sums, W_out->bf16, Wih1->bf16
// ---------------------------------------------------------------------------
__global__ __launch_bounds__(256) void prep_kernel(
    const float* __restrict__ eWhh0, const float* __restrict__ eWih1, const float* __restrict__ eWhh1,
    const float* __restrict__ dWih0, const float* __restrict__ dWhh0, const float* __restrict__ dWih1,
    const float* __restrict__ dWhh1, const float* __restrict__ attWs, const float* __restrict__ attWc,
    const float* __restrict__ cov_w, const float* __restrict__ cov_b,
    const float* __restrict__ e_bih0, const float* __restrict__ e_bhh0,
    const float* __restrict__ e_bih1, const float* __restrict__ e_bhh1,
    const float* __restrict__ d_bih0, const float* __restrict__ d_bhh0,
    const float* __restrict__ d_bih1, const float* __restrict__ d_bhh1,
    const float* __restrict__ W_out,
    unsigned* pkWhh0e, unsigned* pkWih1e, unsigned* pkWhh1e, unsigned* pkWx0d,
    unsigned* pkWhh0d, unsigned* pkWih1d, unsigned* pkWhh1d, unsigned* pkWs,
    float* M3, float* attcb,
    float* b0e, float* b1e, float* b0d, float* b1d,
    unsigned short* Wob, unsigned short* Wib1)
{
    int blk = blockIdx.x, tid = threadIdx.x;
    if (blk < 1856){
        const float* src; int stride, coff, Nj, j0, k0; unsigned* dst;
        if (blk < 1792){
            int mat = blk >> 8, tl = blk & 255;
            switch(mat){
                case 0: src=eWhh0; stride=256; coff=0;   dst=pkWhh0e; break;
                case 1: src=eWih1; stride=256; coff=0;   dst=pkWih1e; break;
                case 2: src=eWhh1; stride=256; coff=0;   dst=pkWhh1e; break;
                case 3: src=dWih0; stride=512; coff=256; dst=pkWx0d;  break;  // ctx cols
                case 4: src=dWhh0; stride=256; coff=0;   dst=pkWhh0d; break;
                case 5: src=dWih1; stride=256; coff=0;   dst=pkWih1d; break;
                default:src=dWhh1; stride=256; coff=0;   dst=pkWhh1d; break;
            }
            Nj = 1024; j0 = (tl>>3)*32; k0 = (tl&7)*32;
        } else {
            int tl = blk - 1792;
            src=attWs; stride=256; coff=0; dst=pkWs;
            Nj = 256; j0 = (tl>>3)*32; k0 = (tl&7)*32;
        }
        __shared__ float t1[32][33];
        int r = tid >> 5, c = tid & 31;
        #pragma unroll
        for (int i=0;i<4;i++)
            t1[r+i*8][c] = src[(size_t)(j0+r+i*8)*stride + coff + k0 + c];
        __syncthreads();
        int k2l = tid >> 5, j = tid & 31;
        #pragma unroll
        for (int i=0;i<2;i++){
            int kq = k2l + i*8;
            dst[(size_t)(k0/2 + kq)*Nj + j0 + j] =
                f2b(t1[j][2*kq]) | (f2b(t1[j][2*kq+1])<<16);
        }
        return;
    }
    if (blk == 1856){
        float m0=0.f,m1=0.f,m2=0.f,cb=0.f;
        for (int c=0;c<64;c++){
            float w = attWc[tid*64+c];
            m0 += w*cov_w[c*3+0]; m1 += w*cov_w[c*3+1]; m2 += w*cov_w[c*3+2];
            cb += w*cov_b[c];
        }
        M3[tid*3+0]=m0; M3[tid*3+1]=m1; M3[tid*3+2]=m2; attcb[tid]=cb;
        return;
    }
    if (blk == 1857){
        for (int i=tid;i<1024;i+=256){
            b0e[i]=e_bih0[i]+e_bhh0[i]; b1e[i]=e_bih1[i]+e_bhh1[i];
            b0d[i]=d_bih0[i]+d_bhh0[i]; b1d[i]=d_bih1[i]+d_bhh1[i];
        }
        return;
    }
    if (blk >= 5858){
        // Wih1 -> bf16 (1024x256 = 262144 elems, 128 blocks x 2048)
        size_t idx = (size_t)(blk-5858)*2048 + tid*8;
        float4 a  = *reinterpret_cast<const float4*>(eWih1+idx);
        float4 b4 = *reinterpret_cast<const float4*>(eWih1+idx+4);
        uint4 o;
        o.x = f2b(a.x)  | (f2b(a.y)<<16);
        o.y = f2b(a.z)  | (f2b(a.w)<<16);
        o.z = f2b(b4.x) | (f2b(b4.y)<<16);
        o.w = f2b(b4.z) | (f2b(b4.w)<<16);
        *reinterpret_cast<uint4*>(Wib1+idx) = o;
        return;
    }
    // W_out -> bf16 (8.192M elems, 4000 blocks x 2048)
    {
        size_t idx = (size_t)(blk-1858)*2048 + tid*8;
        float4 a  = *reinterpret_cast<const float4*>(W_out+idx);
        float4 b4 = *reinterpret_cast<const float4*>(W_out+idx+4);
        uint4 o;
        o.x = f2b(a.x)  | (f2b(a.y)<<16);
        o.y = f2b(a.z)  | (f2b(a.w)<<16);
        o.z = f2b(b4.x) | (f2b(b4.y)<<16);
        o.w = f2b(b4.z) | (f2b(b4.w)<<16);
        *reinterpret_cast<uint4*>(Wob+idx) = o;
    }
}

// ---------------------------------------------------------------------------
// Generic tiled fp32 GEMM: C = A[M,K] @ B[N,K]^T (+bias), A-row gather, split-K
// ---------------------------------------------------------------------------
template<int BM,int BN,int TM,int TN>
__global__ __launch_bounds__(256) void gemm_nt(int M,int N,int K,
    const float* __restrict__ A, int lda,
    const float* __restrict__ B, int ldb,
    float* __restrict__ C, int ldc,
    const float* __restrict__ bias,
    const int* __restrict__ gatherA,
    int Ksl, size_t Cslice)
{
    constexpr int BK=16;
    constexpr int TX=BN/TN, TY=BM/TM;
    static_assert(TX*TY==256, "256 threads");
    __shared__ float As[BK][BM+4];
    __shared__ float Bs[BK][BN+4];
    int tid = threadIdx.x;
    int tx = tid%TX, ty = tid/TX;
    int m0 = blockIdx.y*BM, n0 = blockIdx.x*BN;
    int kz = blockIdx.z;
    int kstart = kz*Ksl, kend = min(K, kstart+Ksl);
    C += (size_t)kz * Cslice;
    const float* bz = (kz==0) ? bias : nullptr;
    float acc[TM][TN] = {};
    int lr = tid>>2, lk = (tid&3)*4;
    for (int k0=kstart;k0<kend;k0+=BK){
        #pragma unroll
        for (int r=lr;r<BM;r+=64){
            int arow = gatherA ? gatherA[m0+r] : (m0+r);
            float4 v = *reinterpret_cast<const float4*>(A + (size_t)arow*lda + k0 + lk);
            As[lk+0][r]=v.x; As[lk+1][r]=v.y; As[lk+2][r]=v.z; As[lk+3][r]=v.w;
        }
        #pragma unroll
        for (int r=lr;r<BN;r+=64){
            float4 v = *reinterpret_cast<const float4*>(B + (size_t)(n0+r)*ldb + k0 + lk);
            Bs[lk+0][r]=v.x; Bs[lk+1][r]=v.y; Bs[lk+2][r]=v.z; Bs[lk+3][r]=v.w;
        }
        __syncthreads();
        #pragma unroll
        for (int k=0;k<BK;k++){
            float a[TM], bv[TN];
            #pragma unroll
            for (int i=0;i<TM;i++) a[i]=As[k][ty*TM+i];
            #pragma unroll
            for (int j=0;j<TN;j++) bv[j]=Bs[k][tx*TN+j];
            #pragma unroll
            for (int i=0;i<TM;i++)
                #pragma unroll
                for (int j=0;j<TN;j++) acc[i][j] += a[i]*bv[j];
        }
        __syncthreads();
    }
    #pragma unroll
    for (int i=0;i<TM;i++){
        size_t m = m0 + ty*TM + i;
        #pragma unroll
        for (int j=0;j<TN;j++){
            int n = n0 + tx*TN + j;
            C[m*ldc + n] = acc[i][j] + (bz ? bz[n] : 0.f);
        }
    }
}

// sum 8 split-K partials -> vp
__global__ __launch_bounds__(256) void vp_reduce(const float* __restrict__ part,
                                                 float* __restrict__ vp)
{
    size_t i = (size_t)blockIdx.x*256 + threadIdx.x;   // float4 index
    const float4* p = reinterpret_cast<const float4*>(part);
    float4 a = p[i];
    #pragma unroll
    for (int s=1;s<8;s++){
        float4 b = p[i + (size_t)s*327680];
        a.x+=b.x; a.y+=b.y; a.z+=b.z; a.w+=b.w;
    }
    reinterpret_cast<float4*>(vp)[i] = a;
}

// ---------------------------------------------------------------------------
// Weight-resident LSTM scan. 64 blocks (1/batch), 512 threads.
// Thread owns gate-rows j=tid and j+512. Weights: k-pairs 0..95 in VGPRs (192),
// k-pairs 96..127 in swizzled LDS (128KB). h broadcast via LDS b128.
// zx rows [b*nsteps+t][1024] include the x-part + bias.
// ---------------------------------------------------------------------------
__global__ __launch_bounds__(512, 2) void lstm_scan(
    int nsteps,
    const float* __restrict__ zx,
    const unsigned* __restrict__ pk,
    unsigned short* __restrict__ hseq,   // [row][256] bf16
    float* __restrict__ outf,            // [row][256] f32 or null
    unsigned short* __restrict__ hfin,   // [b*512 + fin_off + h]
    float* __restrict__ cfin,            // [b*512 + fin_off + h]
    int fin_off)
{
    __shared__ uint4 ws[1024][8];        // 128KB swizzled weight slice
    __shared__ uint4 hp4[32];            // 256 bf16 h as 32 uint4
    __shared__ float zsf[256], zso[256];
    int b = blockIdx.x, tid = threadIdx.x;
    int j0 = tid, j1 = tid + 512;
    // VGPR-resident weights: k2 in [0,96)
    unsigned wv0[96], wv1[96];
    #pragma unroll
    for (int kk=0; kk<96; kk++){
        wv0[kk] = pk[(size_t)kk*1024 + j0];
        wv1[kk] = pk[(size_t)kk*1024 + j1];
    }
    // LDS slice: k2 in [96,128), swizzled for conflict-free b128 row reads
    unsigned* wsu = (unsigned*)ws;
    for (int i = tid; i < 32*1024; i += 512){
        int kk = i >> 10, j = i & 1023;
        wsu[j*32 + (((kk>>2) ^ (j&7))<<2) + (kk&3)] = pk[(size_t)(96+kk)*1024 + j];
    }
    float c = 0.f;
    if (tid < 128) ((unsigned*)hp4)[tid] = 0;
    __syncthreads();
    int p0 = j0 & 7, p1 = j1 & 7;
    for (int t=0; t<nsteps; ++t){
        size_t row = (size_t)b*nsteps + t;
        float zxv0=0.f, zxv1=0.f, zxv2=0.f, zxv3=0.f;
        if (tid < 256){
            const float* zr = zx + row*1024;
            zxv0=zr[tid]; zxv1=zr[tid+256]; zxv2=zr[tid+512]; zxv3=zr[tid+768];
        }
        float a0=0.f,a1=0.f,a2=0.f,a3=0.f;
        #pragma unroll
        for (int g=0; g<24; g++){
            uint4 hc = hp4[g];
            a0=dot2bf(wv0[4*g+0],hc.x,a0); a1=dot2bf(wv1[4*g+0],hc.x,a1);
            a2=dot2bf(wv0[4*g+1],hc.y,a2); a3=dot2bf(wv1[4*g+1],hc.y,a3);
            a0=dot2bf(wv0[4*g+2],hc.z,a0); a1=dot2bf(wv1[4*g+2],hc.z,a1);
            a2=dot2bf(wv0[4*g+3],hc.w,a2); a3=dot2bf(wv1[4*g+3],hc.w,a3);
        }
        #pragma unroll
        for (int g=0; g<8; g++){
            uint4 hc = hp4[24+g];
            uint4 w0 = ws[j0][g ^ p0];
            uint4 w1 = ws[j1][g ^ p1];
            a0=dot2bf(w0.x,hc.x,a0); a1=dot2bf(w1.x,hc.x,a1);
            a2=dot2bf(w0.y,hc.y,a2); a3=dot2bf(w1.y,hc.y,a3);
            a0=dot2bf(w0.z,hc.z,a0); a1=dot2bf(w1.z,hc.z,a1);
            a2=dot2bf(w0.w,hc.w,a2); a3=dot2bf(w1.w,hc.w,a3);
        }
        // thread h<256 owns z_i (a0+a2) and z_g (a1+a3); f,o come from thread h+256
        if (tid >= 256){ zsf[tid-256] = a0+a2; zso[tid-256] = a1+a3; }
        __syncthreads();
        if (tid < 256){
            float i_ = zxv0 + a0+a2;
            float f_ = zxv1 + zsf[tid];
            float g_ = zxv2 + a1+a3;
            float o_ = zxv3 + zso[tid];
            float cn = fsig(f_)*c + fsig(i_)*ftanh(g_);
            c = cn;
            float hn = fsig(o_)*ftanh(cn);
            unsigned short hb = (unsigned short)f2b(hn);
            ((unsigned short*)hp4)[tid] = hb;
            hseq[row*256 + tid] = hb;
            if (outf) outf[row*256 + tid] = hn;
        }
        __syncthreads();
    }
    if (tid < 256){
        hfin[b*512 + fin_off + tid] = ((unsigned short*)hp4)[tid];
        cfin[b*512 + fin_off + tid] = c;
    }
}

// ---------------------------------------------------------------------------
// z1x = h1seq(bf16) @ Wih1(bf16)^T + b1e  -> fp32 [5120][1024]
// grid (16 n-blocks, 80 m-blocks), block 256 = 4 waves x (16m x 64n)
// ---------------------------------------------------------------------------
__global__ __launch_bounds__(256) void z1x_mfma(
    const short* __restrict__ A, const short* __restrict__ Bw,
    const float* __restrict__ bias, float* __restrict__ out)
{
    int w = threadIdx.x >> 6, lane = threadIdx.x & 63;
    int m0 = blockIdx.y*64 + w*16, n0 = blockIdx.x*64;
    int row = lane & 15, kg = lane >> 4;
    const short* arow = A + (size_t)(m0 + row)*256 + kg*8;
    f32x4 acc[4] = {};
    #pragma unroll
    for (int kk=0; kk<8; ++kk){
        bf16x8 a = *reinterpret_cast<const bf16x8*>(arow + kk*32);
        #pragma unroll
        for (int f=0; f<4; ++f){
            bf16x8 bfr = *reinterpret_cast<const bf16x8*>(
                Bw + (size_t)(n0 + f*16 + row)*256 + kk*32 + kg*8);
            acc[f] = __builtin_amdgcn_mfma_f32_16x16x32_bf16(a, bfr, acc[f], 0, 0, 0);
        }
    }
    #pragma unroll
    for (int f=0; f<4; ++f){
        int n = n0 + f*16 + row;
        float bv = bias[n];
        #pragma unroll
        for (int r=0; r<4; ++r){
            int m = m0 + kg*4 + r;
            out[(size_t)m*1024 + n] = acc[f][r] + bv;
        }
    }
}

// ---------------------------------------------------------------------------
// dot phase (decoder): thread computes 4 outputs over ITERS k-pairs
// ---------------------------------------------------------------------------
template<int ITERS>
__device__ __forceinline__ void dot_phase(const unsigned* __restrict__ wbase,
    const unsigned* __restrict__ hu, int k2base, int jq, float* __restrict__ zrow)
{
    float a0=0.f,a1=0.f,a2=0.f,a3=0.f;
    const uint4* wp = (const uint4*)(wbase + (size_t)k2base*1024 + jq*4);
    #pragma unroll 8
    for (int kk=0; kk<ITERS; ++kk){
        uint4 w = wp[(size_t)kk*256];
        unsigned hp = hu[k2base+kk];
        a0=dot2bf(w.x,hp,a0); a1=dot2bf(w.y,hp,a1);
        a2=dot2bf(w.z,hp,a2); a3=dot2bf(w.w,hp,a3);
    }
    zrow[jq*4+0]=a0; zrow[jq*4+1]=a1; zrow[jq*4+2]=a2; zrow[jq*4+3]=a3;
}

// ---------------------------------------------------------------------------
// Decoder scan: one block per batch row, 1024 threads; attn+lstm0+lstm1+LN fused
// ---------------------------------------------------------------------------
__global__ __launch_bounds__(1024) void dec_scan(
    const float* __restrict__ embproj,   // [(b*20+t)*1024] incl bias
    const unsigned* __restrict__ wx0, const unsigned* __restrict__ whh0,
    const unsigned* __restrict__ wih1, const unsigned* __restrict__ whh1,
    const unsigned* __restrict__ pkWs,   // [128 k2][256 h]
    const float* __restrict__ b1d,
    const float* __restrict__ encp, const float* __restrict__ enco,
    const float* __restrict__ att_v, const float* __restrict__ M3,
    const float* __restrict__ attcb,
    const float* __restrict__ ln_g, const float* __restrict__ ln_b,
    const float* __restrict__ encfC, const unsigned short* __restrict__ encfH,
    unsigned short* __restrict__ normedb)
{
    int b = blockIdx.x, tid = threadIdx.x;
    __shared__ unsigned short h1b[256], h2b[256], ctxb[256];
    __shared__ float c1s[256], c2s[256];
    __shared__ float zb[4][1024];
    __shared__ float covs[82], scs[80], attns[80], dps[256];
    __shared__ float red[16];
    int h = tid & 255;
    float bz0=0.f,bz1=0.f,bz2=0.f,bz3=0.f, gg=0.f, bb2=0.f;
    if (tid < 256){
        h1b[tid] = encfH[b*512 + tid];
        h2b[tid] = encfH[b*512 + 256 + tid];
        c1s[tid] = encfC[b*512 + tid];
        c2s[tid] = encfC[b*512 + 256 + tid];
        bz0=b1d[tid]; bz1=b1d[tid+256]; bz2=b1d[tid+512]; bz3=b1d[tid+768];
        gg=ln_g[tid]; bb2=ln_b[tid];
    }
    if (tid < 82) covs[tid] = 0.f;
    int wv = tid >> 6, lane = tid & 63;
    float va[4], m30[4], m31[4], m32[4];
    #pragma unroll
    for (int i=0;i<4;i++){
        int hh = lane + i*64;
        va[i]=att_v[hh]; m30[i]=M3[hh*3]; m31[i]=M3[hh*3+1]; m32[i]=M3[hh*3+2];
    }
    int q   = tid >> 8;        // 0..3
    int jq  = tid & 255;
    int m1  = tid >> 9;
    int ks1 = (tid >> 8) & 1;
    const unsigned* h1u = (const unsigned*)h1b;
    const unsigned* h2u = (const unsigned*)h2b;
    const unsigned* cxu = (const unsigned*)ctxb;
    __syncthreads();
    for (int t=0; t<TT; ++t){
        // ---- attention ----
        {   // dec_proj partials (bf16 dot2, k-split 4)
            float acc = 0.f;
            const unsigned* wp = pkWs + (size_t)(q*32)*256 + h;
            #pragma unroll 8
            for (int kk=0; kk<32; ++kk)
                acc = dot2bf(wp[(size_t)kk*256], h2u[q*32+kk], acc);
            zb[q][h] = acc;
        }
        __syncthreads();
        if (tid < 256) dps[tid] = attcb[tid] + zb[0][tid]+zb[1][tid]+zb[2][tid]+zb[3][tid];
        __syncthreads();
        for (int s = wv*5; s < wv*5+5; ++s){
            float c0=covs[s], c1v=covs[s+1], c2v=covs[s+2];
            float p = 0.f;
            #pragma unroll
            for (int i=0;i<4;i++){
                int hh = lane + i*64;
                float e = encp[((size_t)b*80+s)*256+hh] + dps[hh]
                        + m30[i]*c0 + m31[i]*c1v + m32[i]*c2v;
                p += va[i]*ftanh(e);
            }
            #pragma unroll
            for (int off=32;off;off>>=1) p += __shfl_down(p, off);
            if (lane == 0) scs[s] = p;
        }
        __syncthreads();
        if (tid < 64){
            float a = scs[tid];
            float bsc = (tid < 16) ? scs[tid+64] : -3.4e38f;
            float mx = fmaxf(a, bsc);
            #pragma unroll
            for (int off=32;off;off>>=1) mx = fmaxf(mx, __shfl_xor(mx, off));
            float ea = __expf(a - mx);
            float eb = (tid < 16) ? __expf(bsc - mx) : 0.f;
            float sum = ea + eb;
            #pragma unroll
            for (int off=32;off;off>>=1) sum += __shfl_xor(sum, off);
            float inv = 1.f/sum;
            attns[tid] = ea*inv;
            if (tid < 16) attns[tid+64] = eb*inv;
        }
        __syncthreads();
        if (tid < 80) covs[tid+1] += attns[tid];
        {   // ctx partials (s-split 4)
            float acc = 0.f;
            for (int s=q*20; s<q*20+20; ++s)
                acc += attns[s]*enco[((size_t)b*80+s)*256 + h];
            zb[q][h] = acc;
        }
        __syncthreads();
        if (tid < 256)
            ctxb[h] = (unsigned short)f2b(zb[0][h]+zb[1][h]+zb[2][h]+zb[3][h]);
        float ep0=0.f,ep1=0.f,ep2=0.f,ep3=0.f;
        if (tid < 256){
            const float* er = embproj + ((size_t)b*TT + t)*1024;
            ep0=er[h]; ep1=er[h+256]; ep2=er[h+512]; ep3=er[h+768];
        }
        __syncthreads();
        // ---- lstm0: x = ctx (wx0), h = h1 (whh0) ----
        dot_phase<64>(m1 ? whh0 : wx0, m1 ? h1u : cxu, ks1*64, jq, &zb[m1*2+ks1][0]);
        __syncthreads();
        if (tid < 256){
            float i_ = ep0+zb[0][h]+zb[1][h]+zb[2][h]+zb[3][h];
            float f_ = ep1+zb[0][h+256]+zb[1][h+256]+zb[2][h+256]+zb[3][h+256];
            float g_ = ep2+zb[0][h+512]+zb[1][h+512]+zb[2][h+512]+zb[3][h+512];
            float o_ = ep3+zb[0][h+768]+zb[1][h+768]+zb[2][h+768]+zb[3][h+768];
            float cn = fsig(f_)*c1s[h] + fsig(i_)*ftanh(g_);
            c1s[h] = cn;
            h1b[h] = (unsigned short)f2b(fsig(o_)*ftanh(cn));
        }
        __syncthreads();
        // ---- lstm1: x = h1 (wih1), h = h2 (whh1) ----
        dot_phase<64>(m1 ? whh1 : wih1, m1 ? h2u : h1u, ks1*64, jq, &zb[m1*2+ks1][0]);
        __syncthreads();
        float hn = 0.f;
        if (tid < 256){
            float i_ = bz0+zb[0][h]+zb[1][h]+zb[2][h]+zb[3][h];
            float f_ = bz1+zb[0][h+256]+zb[1][h+256]+zb[2][h+256]+zb[3][h+256];
            float g_ = bz2+zb[0][h+512]+zb[1][h+512]+zb[2][h+512]+zb[3][h+512];
            float o_ = bz3+zb[0][h+768]+zb[1][h+768]+zb[2][h+768]+zb[3][h+768];
            float cn = fsig(f_)*c2s[h] + fsig(i_)*ftanh(g_);
            c2s[h] = cn;
            hn = fsig(o_)*ftanh(cn);
            h2b[h] = (unsigned short)f2b(hn);
        }
        // fused LayerNorm over h2
        float s1 = hn;
        #pragma unroll
        for (int off=32;off;off>>=1) s1 += __shfl_xor(s1, off);
        if (lane == 0) red[wv] = s1;
        __syncthreads();
        float mean = (red[0]+red[1]+red[2]+red[3]) * (1.f/256.f);
        __syncthreads();
        float d = (tid < 256) ? (hn - mean) : 0.f;
        float s2 = d*d;
        #pragma unroll
        for (int off=32;off;off>>=1) s2 += __shfl_xor(s2, off);
        if (lane == 0) red[wv] = s2;
        __syncthreads();
        float var = (red[0]+red[1]+red[2]+red[3]) * (1.f/256.f);
        if (tid < 256)
            normedb[((size_t)b*TT + t)*256 + h] =
                (unsigned short)f2b(d*rsqrtf(var + 1e-5f)*gg + bb2);
        __syncthreads();
    }
}

// ---------------------------------------------------------------------------
// Logits: bf16 MFMA, W-stationary. Block = 64 n-cols; loops all 80 m-tiles.
// ---------------------------------------------------------------------------
__global__ __launch_bounds__(256) void logits_mfma(
    const short* __restrict__ A, const short* __restrict__ Bw,
    const float* __restrict__ bias, float* __restrict__ out)
{
    int w = threadIdx.x >> 6, lane = threadIdx.x & 63;
    int n0 = blockIdx.x*64 + w*16;
    int row = lane & 15, kg = lane >> 4;
    bf16x8 bfr[8];
    const short* brow = Bw + (size_t)(n0 + row)*256 + kg*8;
    #pragma unroll
    for (int kk=0;kk<8;kk++) bfr[kk] = *reinterpret_cast<const bf16x8*>(brow + kk*32);
    float bv = bias[n0 + row];
    for (int mt=0; mt<80; ++mt){
        int m0 = mt*16;
        const short* arow = A + (size_t)(m0 + row)*256 + kg*8;
        f32x4 acc = {};
        #pragma unroll
        for (int kk=0;kk<8;kk++){
            bf16x8 a = *reinterpret_cast<const bf16x8*>(arow + kk*32);
            acc = __builtin_amdgcn_mfma_f32_16x16x32_bf16(a, bfr[kk], acc, 0, 0, 0);
        }
        #pragma unroll
        for (int r=0;r<4;r++){
            int m = m0 + kg*4 + r;
            out[(size_t)m*VV + n0 + row] = acc[r] + bv;
        }
    }
}

// ---------------------------------------------------------------------------
extern "C" void kernel_launch(void* const* d_in, const int* in_sizes, int n_in,
                              void* d_out, int out_size, void* d_ws, size_t ws_size,
                              hipStream_t stream)
{
    const float* video  = (const float*)d_in[0];
    const int*   caps   = (const int*)  d_in[1];
    const float* W_vp   = (const float*)d_in[2];
    const float* b_vp   = (const float*)d_in[3];
    const float* eWih0  = (const float*)d_in[4];
    const float* eWhh0  = (const float*)d_in[5];
    const float* e_bih0 = (const float*)d_in[6];
    const float* e_bhh0 = (const float*)d_in[7];
    const float* eWih1  = (const float*)d_in[8];
    const float* eWhh1  = (const float*)d_in[9];
    const float* e_bih1 = (const float*)d_in[10];
    const float* e_bhh1 = (const float*)d_in[11];
    const float* emb    = (const float*)d_in[12];
    const float* dWih0  = (const float*)d_in[13];
    const float* dWhh0  = (const float*)d_in[14];
    const float* d_bih0 = (const float*)d_in[15];
    const float* d_bhh0 = (const float*)d_in[16];
    const float* dWih1  = (const float*)d_in[17];
    const float* dWhh1  = (const float*)d_in[18];
    const float* d_bih1 = (const float*)d_in[19];
    const float* d_bhh1 = (const float*)d_in[20];
    const float* attWh  = (const float*)d_in[21];
    const float* attWs  = (const float*)d_in[22];
    const float* att_v  = (const float*)d_in[23];
    const float* attWc  = (const float*)d_in[24];
    const float* cov_w  = (const float*)d_in[25];
    const float* cov_b  = (const float*)d_in[26];
    const float* ln_g   = (const float*)d_in[27];
    const float* ln_b   = (const float*)d_in[28];
    const float* W_out  = (const float*)d_in[29];
    const float* b_out  = (const float*)d_in[30];
    float* out = (float*)d_out;

    float* W = (float*)d_ws;
    size_t o = 0;
    auto alloc = [&](size_t n){ size_t r = o; o += ((n + 63)/64)*64; return r; };

    // big shared region R: vp_part (8 x 5120x256) overlaps {zx0, embproj}
    float* R       = W + alloc((size_t)8*SS*BB*HH);     // 10,485,760 floats
    float* vp_part = R;
    float* zx0     = R;                                  // [(b*80+t)*1024]
    float* embproj = R + (size_t)SS*BB*1024;             // [(b*20+t)*1024]
    float* vp      = W + alloc((size_t)SS*BB*HH);        // [b*80+t][256]
    float* z1x     = W + alloc((size_t)SS*BB*1024);      // [(b*80+t)*1024]
    float* enc_out = W + alloc((size_t)BB*SS*HH);        // [(b*80+t)*256]
    float* encproj = W + alloc((size_t)BB*SS*HH);
    unsigned short* normedb = (unsigned short*)(W + alloc((size_t)BB*TT*HH/2));
    unsigned short* h1seq = (unsigned short*)(W + alloc((size_t)SS*BB*HH/2));
    unsigned short* h2seq = (unsigned short*)(W + alloc((size_t)SS*BB*HH/2));
    float* encfC   = W + alloc(BB*512);
    unsigned short* encfH = (unsigned short*)(W + alloc(BB*256));
    unsigned* pkWhh0e = (unsigned*)(W + alloc(128*1024));
    unsigned* pkWih1e = (unsigned*)(W + alloc(128*1024));
    unsigned* pkWhh1e = (unsigned*)(W + alloc(128*1024));
    unsigned* pkWx0d  = (unsigned*)(W + alloc(128*1024));
    unsigned* pkWhh0d = (unsigned*)(W + alloc(128*1024));
    unsigned* pkWih1d = (unsigned*)(W + alloc(128*1024));
    unsigned* pkWhh1d = (unsigned*)(W + alloc(128*1024));
    unsigned* pkWs    = (unsigned*)(W + alloc(128*256));
    float* M3      = W + alloc(768);
    float* attcb   = W + alloc(256);
    float* b0e     = W + alloc(1024);
    float* b1e     = W + alloc(1024);
    float* b0d     = W + alloc(1024);
    float* b1d     = W + alloc(1024);
    unsigned short* Wob  = (unsigned short*)(W + alloc((size_t)VV*HH/2));
    unsigned short* Wib1 = (unsigned short*)(W + alloc(1024*HH/2));
    (void)ws_size; (void)n_in; (void)in_sizes; (void)out_size;

    prep_kernel<<<5986, 256, 0, stream>>>(
        eWhh0, eWih1, eWhh1, dWih0, dWhh0, dWih1, dWhh1, attWs, attWc,
        cov_w, cov_b, e_bih0, e_bhh0, e_bih1, e_bhh1, d_bih0, d_bhh0, d_bih1, d_bhh1,
        W_out,
        pkWhh0e, pkWih1e, pkWhh1e, pkWx0d, pkWhh0d, pkWih1d, pkWhh1d, pkWs,
        M3, attcb, b0e, b1e, b0d, b1d, Wob, Wib1);

    // vp = video @ W_vp^T + b_vp  (5120x256, K=4096) split-K x8
    gemm_nt<64,64,4,4><<<dim3(4,80,8), 256, 0, stream>>>(
        SS*BB, HH, FF, video, FF, W_vp, FF, vp_part, HH, b_vp, nullptr,
        512, (size_t)SS*BB*HH);
    vp_reduce<<<1280, 256, 0, stream>>>(vp_part, vp);

    // zx0[b*80+t] = vp @ eWih0^T + (bih0+bhh0)   (5120x1024, K=256)
    gemm_nt<64,64,4,4><<<dim3(16,80), 256, 0, stream>>>(
        SS*BB, 1024, HH, vp, HH, eWih0, HH, zx0, 1024, b0e, nullptr, HH, 0);

    // embproj[b*20+t] = emb[cap] @ dWih0[:, :256]^T + (bih0+bhh0)  (1280x1024, K=256)
    gemm_nt<64,64,4,4><<<dim3(16,20), 256, 0, stream>>>(
        TT*BB, 1024, HH, emb, HH, dWih0, 512, embproj, 1024, b0d, caps, HH, 0);

    // encoder layer0 scan (weight-resident)
    lstm_scan<<<64, 512, 0, stream>>>(SS, zx0, pkWhh0e, h1seq, nullptr,
                                      encfH, encfC, 0);

    // z1x = h1seq @ Wih1^T + b1e  (5120x1024, K=256, bf16 MFMA)
    z1x_mfma<<<dim3(16, 80), 256, 0, stream>>>(
        (const short*)h1seq, (const short*)Wib1, b1e, z1x);

    // encoder layer1 scan (weight-resident), writes enc_out fp32 + finals
    lstm_scan<<<64, 512, 0, stream>>>(SS, z1x, pkWhh1e, h2seq, enc_out,
                                      encfH, encfC, 256);

    // enc_proj = enc_out @ att_Wh^T  (5120x256, K=256)
    gemm_nt<64,64,4,4><<<dim3(4,80), 256, 0, stream>>>(
        SS*BB, HH, HH, enc_out, HH, attWh, HH, encproj, HH, nullptr, nullptr, HH, 0);

    // decoder scan: 64 per-batch blocks (attn + lstm0 + lstm1 + LN fused)
    dec_scan<<<64, 1024, 0, stream>>>(embproj, pkWx0d, pkWhh0d, pkWih1d, pkWhh1d,
                                      pkWs, b1d, encproj, enc_out, att_v, M3, attcb,
                                      ln_g, ln_b, encfC, encfH, normedb);

    // logits = normed @ W_out^T + b_out  (1280 x 32000, K=256)
    logits_mfma<<<VV/64, 256, 0, stream>>>(
        (const short*)normedb, (const short*)Wob, b_out, out);
}

// Round 6
// 1263.776 us; speedup vs baseline: 6.3513x; 1.2173x over previous
//
#include <hip/hip_runtime.h>
#include <math.h>

// Problem constants
#define BB 64
#define SS 80
#define TT 20
#define FF 4096
#define HH 256
#define VV 32000

typedef __attribute__((ext_vector_type(8))) short bf16x8;
typedef __attribute__((ext_vector_type(4))) float f32x4;

__device__ __forceinline__ float fsig(float x){ return 1.f/(1.f+__expf(-x)); }
__device__ __forceinline__ float ftanh(float x){
    float xc = fminf(fmaxf(x,-15.f),15.f);
    float e = __expf(2.f*xc);
    return (e-1.f)/(e+1.f);
}
__device__ __forceinline__ unsigned int f2b(float x){
    unsigned int u = __float_as_uint(x);
    return (u + 0x7fffu + ((u>>16)&1u)) >> 16;
}
__device__ __forceinline__ float b2f(unsigned short u){
    return __uint_as_float(((unsigned)u)<<16);
}
// acc += dot2(bf16pair w, bf16pair h)  -- CDNA v_dot2_f32_bf16
__device__ __forceinline__ float dot2bf(unsigned w, unsigned hp, float acc){
    float r;
    asm("v_dot2_f32_bf16 %0, %1, %2, %3" : "=v"(r) : "v"(w), "v"(hp), "v"(acc));
    return r;
}

// ---------------------------------------------------------------------------
// prep: k-pair-packed bf16 weights pk[k2*Nj + j] = bf16 W[j][2k2] | bf16 W[j][2k2+1]<<16
// matrices 0..6 (Nj=1024), 7 = attWs (Nj=256); M3, bias sums; W_out/Wih1/attWh -> bf16
// ---------------------------------------------------------------------------
__global__ __launch_bounds__(256) void prep_kernel(
    const float* __restrict__ eWhh0, const float* __restrict__ eWih1, const float* __restrict__ eWhh1,
    const float* __restrict__ dWih0, const float* __restrict__ dWhh0, const float* __restrict__ dWih1,
    const float* __restrict__ dWhh1, const float* __restrict__ attWs, const float* __restrict__ attWc,
    const float* __restrict__ cov_w, const float* __restrict__ cov_b,
    const float* __restrict__ e_bih0, const float* __restrict__ e_bhh0,
    const float* __restrict__ e_bih1, const float* __restrict__ e_bhh1,
    const float* __restrict__ d_bih0, const float* __restrict__ d_bhh0,
    const float* __restrict__ d_bih1, const float* __restrict__ d_bhh1,
    const float* __restrict__ W_out, const float* __restrict__ attWh,
    unsigned* pkWhh0e, unsigned* pkWih1e, unsigned* pkWhh1e, unsigned* pkWx0d,
    unsigned* pkWhh0d, unsigned* pkWih1d, unsigned* pkWhh1d, unsigned* pkWs,
    float* M3, float* attcb,
    float* b0e, float* b1e, float* b0d, float* b1d,
    unsigned short* Wob, unsigned short* Wib1, unsigned short* Whb)
{
    int blk = blockIdx.x, tid = threadIdx.x;
    if (blk < 1856){
        const float* src; int stride, coff, Nj, j0, k0; unsigned* dst;
        if (blk < 1792){
            int mat = blk >> 8, tl = blk & 255;
            switch(mat){
                case 0: src=eWhh0; stride=256; coff=0;   dst=pkWhh0e; break;
                case 1: src=eWih1; stride=256; coff=0;   dst=pkWih1e; break;
                case 2: src=eWhh1; stride=256; coff=0;   dst=pkWhh1e; break;
                case 3: src=dWih0; stride=512; coff=256; dst=pkWx0d;  break;  // ctx cols
                case 4: src=dWhh0; stride=256; coff=0;   dst=pkWhh0d; break;
                case 5: src=dWih1; stride=256; coff=0;   dst=pkWih1d; break;
                default:src=dWhh1; stride=256; coff=0;   dst=pkWhh1d; break;
            }
            Nj = 1024; j0 = (tl>>3)*32; k0 = (tl&7)*32;
        } else {
            int tl = blk - 1792;
            src=attWs; stride=256; coff=0; dst=pkWs;
            Nj = 256; j0 = (tl>>3)*32; k0 = (tl&7)*32;
        }
        __shared__ float t1[32][33];
        int r = tid >> 5, c = tid & 31;
        #pragma unroll
        for (int i=0;i<4;i++)
            t1[r+i*8][c] = src[(size_t)(j0+r+i*8)*stride + coff + k0 + c];
        __syncthreads();
        int k2l = tid >> 5, j = tid & 31;
        #pragma unroll
        for (int i=0;i<2;i++){
            int kq = k2l + i*8;
            dst[(size_t)(k0/2 + kq)*Nj + j0 + j] =
                f2b(t1[j][2*kq]) | (f2b(t1[j][2*kq+1])<<16);
        }
        return;
    }
    if (blk == 1856){
        float m0=0.f,m1=0.f,m2=0.f,cb=0.f;
        for (int c=0;c<64;c++){
            float w = attWc[tid*64+c];
            m0 += w*cov_w[c*3+0]; m1 += w*cov_w[c*3+1]; m2 += w*cov_w[c*3+2];
            cb += w*cov_b[c];
        }
        M3[tid*3+0]=m0; M3[tid*3+1]=m1; M3[tid*3+2]=m2; attcb[tid]=cb;
        return;
    }
    if (blk == 1857){
        for (int i=tid;i<1024;i+=256){
            b0e[i]=e_bih0[i]+e_bhh0[i]; b1e[i]=e_bih1[i]+e_bhh1[i];
            b0d[i]=d_bih0[i]+d_bhh0[i]; b1d[i]=d_bih1[i]+d_bhh1[i];
        }
        return;
    }
    // bf16 conversions
    const float* csrc; unsigned short* cdst; size_t base;
    if (blk >= 5986){       // attWh: 65536 elems, 32 blocks
        csrc = attWh; cdst = Whb; base = (size_t)(blk-5986)*2048;
    } else if (blk >= 5858){ // eWih1: 262144 elems, 128 blocks
        csrc = eWih1; cdst = Wib1; base = (size_t)(blk-5858)*2048;
    } else {                 // W_out: 8.192M elems, 4000 blocks
        csrc = W_out; cdst = Wob; base = (size_t)(blk-1858)*2048;
    }
    {
        size_t idx = base + tid*8;
        float4 a  = *reinterpret_cast<const float4*>(csrc+idx);
        float4 b4 = *reinterpret_cast<const float4*>(csrc+idx+4);
        uint4 o;
        o.x = f2b(a.x)  | (f2b(a.y)<<16);
        o.y = f2b(a.z)  | (f2b(a.w)<<16);
        o.z = f2b(b4.x) | (f2b(b4.y)<<16);
        o.w = f2b(b4.z) | (f2b(b4.w)<<16);
        *reinterpret_cast<uint4*>(cdst+idx) = o;
    }
}

// ---------------------------------------------------------------------------
// Generic tiled fp32 GEMM: C = A[M,K] @ B[N,K]^T (+bias), A-row gather, split-K
// ---------------------------------------------------------------------------
template<int BM,int BN,int TM,int TN>
__global__ __launch_bounds__(256) void gemm_nt(int M,int N,int K,
    const float* __restrict__ A, int lda,
    const float* __restrict__ B, int ldb,
    float* __restrict__ C, int ldc,
    const float* __restrict__ bias,
    const int* __restrict__ gatherA,
    int Ksl, size_t Cslice)
{
    constexpr int BK=16;
    constexpr int TX=BN/TN, TY=BM/TM;
    static_assert(TX*TY==256, "256 threads");
    __shared__ float As[BK][BM+4];
    __shared__ float Bs[BK][BN+4];
    int tid = threadIdx.x;
    int tx = tid%TX, ty = tid/TX;
    int m0 = blockIdx.y*BM, n0 = blockIdx.x*BN;
    int kz = blockIdx.z;
    int kstart = kz*Ksl, kend = min(K, kstart+Ksl);
    C += (size_t)kz * Cslice;
    const float* bz = (kz==0) ? bias : nullptr;
    float acc[TM][TN] = {};
    int lr = tid>>2, lk = (tid&3)*4;
    for (int k0=kstart;k0<kend;k0+=BK){
        #pragma unroll
        for (int r=lr;r<BM;r+=64){
            int arow = gatherA ? gatherA[m0+r] : (m0+r);
            float4 v = *reinterpret_cast<const float4*>(A + (size_t)arow*lda + k0 + lk);
            As[lk+0][r]=v.x; As[lk+1][r]=v.y; As[lk+2][r]=v.z; As[lk+3][r]=v.w;
        }
        #pragma unroll
        for (int r=lr;r<BN;r+=64){
            float4 v = *reinterpret_cast<const float4*>(B + (size_t)(n0+r)*ldb + k0 + lk);
            Bs[lk+0][r]=v.x; Bs[lk+1][r]=v.y; Bs[lk+2][r]=v.z; Bs[lk+3][r]=v.w;
        }
        __syncthreads();
        #pragma unroll
        for (int k=0;k<BK;k++){
            float a[TM], bv[TN];
            #pragma unroll
            for (int i=0;i<TM;i++) a[i]=As[k][ty*TM+i];
            #pragma unroll
            for (int j=0;j<TN;j++) bv[j]=Bs[k][tx*TN+j];
            #pragma unroll
            for (int i=0;i<TM;i++)
                #pragma unroll
                for (int j=0;j<TN;j++) acc[i][j] += a[i]*bv[j];
        }
        __syncthreads();
    }
    #pragma unroll
    for (int i=0;i<TM;i++){
        size_t m = m0 + ty*TM + i;
        #pragma unroll
        for (int j=0;j<TN;j++){
            int n = n0 + tx*TN + j;
            C[m*ldc + n] = acc[i][j] + (bz ? bz[n] : 0.f);
        }
    }
}

// sum 8 split-K partials -> vp
__global__ __launch_bounds__(256) void vp_reduce(const float* __restrict__ part,
                                                 float* __restrict__ vp)
{
    size_t i = (size_t)blockIdx.x*256 + threadIdx.x;   // float4 index
    const float4* p = reinterpret_cast<const float4*>(part);
    float4 a = p[i];
    #pragma unroll
    for (int s=1;s<8;s++){
        float4 b = p[i + (size_t)s*327680];
        a.x+=b.x; a.y+=b.y; a.z+=b.z; a.w+=b.w;
    }
    reinterpret_cast<float4*>(vp)[i] = a;
}

// ---------------------------------------------------------------------------
// Weight-resident LSTM scan. 64 blocks (1/batch), 512 threads.
// Thread owns gate-rows j=tid and j+512. Weights: k-pairs 0..95 in VGPRs (192),
// k-pairs 96..127 in swizzled LDS (128KB). h broadcast via LDS b128.
// zx rows [b*nsteps+t][1024] include the x-part + bias.
// ---------------------------------------------------------------------------
__global__ __launch_bounds__(512, 2) void lstm_scan(
    int nsteps,
    const float* __restrict__ zx,
    const unsigned* __restrict__ pk,
    unsigned short* __restrict__ hseq,   // [row][256] bf16
    float* __restrict__ outf,            // [row][256] f32 or null
    unsigned short* __restrict__ hfin,   // [b*512 + fin_off + h]
    float* __restrict__ cfin,            // [b*512 + fin_off + h]
    int fin_off)
{
    __shared__ uint4 ws[1024][8];        // 128KB swizzled weight slice
    __shared__ uint4 hp4[32];            // 256 bf16 h as 32 uint4
    __shared__ float zsf[256], zso[256];
    int b = blockIdx.x, tid = threadIdx.x;
    int j0 = tid, j1 = tid + 512;
    // VGPR-resident weights: k2 in [0,96)
    unsigned wv0[96], wv1[96];
    #pragma unroll
    for (int kk=0; kk<96; kk++){
        wv0[kk] = pk[(size_t)kk*1024 + j0];
        wv1[kk] = pk[(size_t)kk*1024 + j1];
    }
    // LDS slice: k2 in [96,128), swizzled for conflict-free b128 row reads
    unsigned* wsu = (unsigned*)ws;
    for (int i = tid; i < 32*1024; i += 512){
        int kk = i >> 10, j = i & 1023;
        wsu[j*32 + (((kk>>2) ^ (j&7))<<2) + (kk&3)] = pk[(size_t)(96+kk)*1024 + j];
    }
    float c = 0.f;
    if (tid < 128) ((unsigned*)hp4)[tid] = 0;
    __syncthreads();
    int p0 = j0 & 7, p1 = j1 & 7;
    for (int t=0; t<nsteps; ++t){
        size_t row = (size_t)b*nsteps + t;
        float zxv0=0.f, zxv1=0.f, zxv2=0.f, zxv3=0.f;
        if (tid < 256){
            const float* zr = zx + row*1024;
            zxv0=zr[tid]; zxv1=zr[tid+256]; zxv2=zr[tid+512]; zxv3=zr[tid+768];
        }
        float a0=0.f,a1=0.f,a2=0.f,a3=0.f;
        #pragma unroll
        for (int g=0; g<24; g++){
            uint4 hc = hp4[g];
            a0=dot2bf(wv0[4*g+0],hc.x,a0); a1=dot2bf(wv1[4*g+0],hc.x,a1);
            a2=dot2bf(wv0[4*g+1],hc.y,a2); a3=dot2bf(wv1[4*g+1],hc.y,a3);
            a0=dot2bf(wv0[4*g+2],hc.z,a0); a1=dot2bf(wv1[4*g+2],hc.z,a1);
            a2=dot2bf(wv0[4*g+3],hc.w,a2); a3=dot2bf(wv1[4*g+3],hc.w,a3);
        }
        #pragma unroll
        for (int g=0; g<8; g++){
            uint4 hc = hp4[24+g];
            uint4 w0 = ws[j0][g ^ p0];
            uint4 w1 = ws[j1][g ^ p1];
            a0=dot2bf(w0.x,hc.x,a0); a1=dot2bf(w1.x,hc.x,a1);
            a2=dot2bf(w0.y,hc.y,a2); a3=dot2bf(w1.y,hc.y,a3);
            a0=dot2bf(w0.z,hc.z,a0); a1=dot2bf(w1.z,hc.z,a1);
            a2=dot2bf(w0.w,hc.w,a2); a3=dot2bf(w1.w,hc.w,a3);
        }
        // thread h<256 owns z_i (a0+a2) and z_g (a1+a3); f,o come from thread h+256
        if (tid >= 256){ zsf[tid-256] = a0+a2; zso[tid-256] = a1+a3; }
        __syncthreads();
        if (tid < 256){
            float i_ = zxv0 + a0+a2;
            float f_ = zxv1 + zsf[tid];
            float g_ = zxv2 + a1+a3;
            float o_ = zxv3 + zso[tid];
            float cn = fsig(f_)*c + fsig(i_)*ftanh(g_);
            c = cn;
            float hn = fsig(o_)*ftanh(cn);
            unsigned short hb = (unsigned short)f2b(hn);
            ((unsigned short*)hp4)[tid] = hb;
            hseq[row*256 + tid] = hb;
            if (outf) outf[row*256 + tid] = hn;
        }
        __syncthreads();
    }
    if (tid < 256){
        hfin[b*512 + fin_off + tid] = ((unsigned short*)hp4)[tid];
        cfin[b*512 + fin_off + tid] = c;
    }
}

// ---------------------------------------------------------------------------
// z1x = h1seq(bf16) @ Wih1(bf16)^T + b1e  -> fp32 [5120][1024]
// ---------------------------------------------------------------------------
__global__ __launch_bounds__(256) void z1x_mfma(
    const short* __restrict__ A, const short* __restrict__ Bw,
    const float* __restrict__ bias, float* __restrict__ out)
{
    int w = threadIdx.x >> 6, lane = threadIdx.x & 63;
    int m0 = blockIdx.y*64 + w*16, n0 = blockIdx.x*64;
    int row = lane & 15, kg = lane >> 4;
    const short* arow = A + (size_t)(m0 + row)*256 + kg*8;
    f32x4 acc[4] = {};
    #pragma unroll
    for (int kk=0; kk<8; ++kk){
        bf16x8 a = *reinterpret_cast<const bf16x8*>(arow + kk*32);
        #pragma unroll
        for (int f=0; f<4; ++f){
            bf16x8 bfr = *reinterpret_cast<const bf16x8*>(
                Bw + (size_t)(n0 + f*16 + row)*256 + kk*32 + kg*8);
            acc[f] = __builtin_amdgcn_mfma_f32_16x16x32_bf16(a, bfr, acc[f], 0, 0, 0);
        }
    }
    #pragma unroll
    for (int f=0; f<4; ++f){
        int n = n0 + f*16 + row;
        float bv = bias[n];
        #pragma unroll
        for (int r=0; r<4; ++r){
            int m = m0 + kg*4 + r;
            out[(size_t)m*1024 + n] = acc[f][r] + bv;
        }
    }
}

// ---------------------------------------------------------------------------
// encp = h2seq(bf16) @ attWh(bf16)^T -> bf16 [5120][256]
// ---------------------------------------------------------------------------
__global__ __launch_bounds__(256) void encp_mfma(
    const short* __restrict__ A, const short* __restrict__ Bw,
    unsigned short* __restrict__ out)
{
    int w = threadIdx.x >> 6, lane = threadIdx.x & 63;
    int m0 = blockIdx.y*64 + w*16, n0 = blockIdx.x*64;
    int row = lane & 15, kg = lane >> 4;
    const short* arow = A + (size_t)(m0 + row)*256 + kg*8;
    f32x4 acc[4] = {};
    #pragma unroll
    for (int kk=0; kk<8; ++kk){
        bf16x8 a = *reinterpret_cast<const bf16x8*>(arow + kk*32);
        #pragma unroll
        for (int f=0; f<4; ++f){
            bf16x8 bfr = *reinterpret_cast<const bf16x8*>(
                Bw + (size_t)(n0 + f*16 + row)*256 + kk*32 + kg*8);
            acc[f] = __builtin_amdgcn_mfma_f32_16x16x32_bf16(a, bfr, acc[f], 0, 0, 0);
        }
    }
    #pragma unroll
    for (int f=0; f<4; ++f){
        int n = n0 + f*16 + row;
        #pragma unroll
        for (int r=0; r<4; ++r){
            int m = m0 + kg*4 + r;
            out[(size_t)m*256 + n] = (unsigned short)f2b(acc[f][r]);
        }
    }
}

// ---------------------------------------------------------------------------
// dot phase (decoder): thread computes 4 outputs over ITERS k-pairs
// ---------------------------------------------------------------------------
template<int ITERS>
__device__ __forceinline__ void dot_phase(const unsigned* __restrict__ wbase,
    const unsigned* __restrict__ hu, int k2base, int jq, float* __restrict__ zrow)
{
    float a0=0.f,a1=0.f,a2=0.f,a3=0.f;
    const uint4* wp = (const uint4*)(wbase + (size_t)k2base*1024 + jq*4);
    #pragma unroll 8
    for (int kk=0; kk<ITERS; ++kk){
        uint4 w = wp[(size_t)kk*256];
        unsigned hp = hu[k2base+kk];
        a0=dot2bf(w.x,hp,a0); a1=dot2bf(w.y,hp,a1);
        a2=dot2bf(w.z,hp,a2); a3=dot2bf(w.w,hp,a3);
    }
    zrow[jq*4+0]=a0; zrow[jq*4+1]=a1; zrow[jq*4+2]=a2; zrow[jq*4+3]=a3;
}

// ---------------------------------------------------------------------------
// Decoder scan: one block per batch row, 1024 threads; attn+lstm0+lstm1+LN fused.
// encp/enco (bf16) staged into LDS once -> per-step L2 stream = weights only.
// ---------------------------------------------------------------------------
__global__ __launch_bounds__(1024) void dec_scan(
    const float* __restrict__ embproj,   // [(b*20+t)*1024] incl bias
    const unsigned* __restrict__ wx0, const unsigned* __restrict__ whh0,
    const unsigned* __restrict__ wih1, const unsigned* __restrict__ whh1,
    const unsigned* __restrict__ pkWs,   // [128 k2][256 h]
    const float* __restrict__ b1d,
    const unsigned short* __restrict__ encp,  // [5120][256] bf16
    const unsigned short* __restrict__ enco,  // [5120][256] bf16 (= h2seq)
    const float* __restrict__ att_v, const float* __restrict__ M3,
    const float* __restrict__ attcb,
    const float* __restrict__ ln_g, const float* __restrict__ ln_b,
    const float* __restrict__ encfC, const unsigned short* __restrict__ encfH,
    unsigned short* __restrict__ normedb)
{
    int b = blockIdx.x, tid = threadIdx.x;
    __shared__ unsigned short encpL[SS*256];   // 40KB
    __shared__ unsigned short encoL[SS*256];   // 40KB
    __shared__ unsigned short h1b[256], h2b[256], ctxb[256];
    __shared__ float c1s[256], c2s[256];
    __shared__ float zb[4][1024];
    __shared__ float covs[82], scs[80], attns[80], dps[256];
    __shared__ float red[16];
    // stage encp/enco slices for this batch into LDS (once)
    {
        const uint4* sp = (const uint4*)(encp + (size_t)b*SS*256);
        const uint4* so = (const uint4*)(enco + (size_t)b*SS*256);
        uint4* dp = (uint4*)encpL;
        uint4* dq = (uint4*)encoL;
        for (int i=tid; i<SS*256/8; i+=1024){ dp[i] = sp[i]; dq[i] = so[i]; }
    }
    int h = tid & 255;
    float bz0=0.f,bz1=0.f,bz2=0.f,bz3=0.f, gg=0.f, bb2=0.f;
    if (tid < 256){
        h1b[tid] = encfH[b*512 + tid];
        h2b[tid] = encfH[b*512 + 256 + tid];
        c1s[tid] = encfC[b*512 + tid];
        c2s[tid] = encfC[b*512 + 256 + tid];
        bz0=b1d[tid]; bz1=b1d[tid+256]; bz2=b1d[tid+512]; bz3=b1d[tid+768];
        gg=ln_g[tid]; bb2=ln_b[tid];
    }
    if (tid < 82) covs[tid] = 0.f;
    int wv = tid >> 6, lane = tid & 63;
    float va[4], m30[4], m31[4], m32[4];
    #pragma unroll
    for (int i=0;i<4;i++){
        int hh = lane + i*64;
        va[i]=att_v[hh]; m30[i]=M3[hh*3]; m31[i]=M3[hh*3+1]; m32[i]=M3[hh*3+2];
    }
    int q   = tid >> 8;        // 0..3
    int jq  = tid & 255;
    int m1  = tid >> 9;
    int ks1 = (tid >> 8) & 1;
    const unsigned* h1u = (const unsigned*)h1b;
    const unsigned* h2u = (const unsigned*)h2b;
    const unsigned* cxu = (const unsigned*)ctxb;
    __syncthreads();
    for (int t=0; t<TT; ++t){
        // ---- attention ----
        {   // dec_proj partials (bf16 dot2, k-split 4)
            float acc = 0.f;
            const unsigned* wp = pkWs + (size_t)(q*32)*256 + h;
            #pragma unroll 8
            for (int kk=0; kk<32; ++kk)
                acc = dot2bf(wp[(size_t)kk*256], h2u[q*32+kk], acc);
            zb[q][h] = acc;
        }
        __syncthreads();
        if (tid < 256) dps[tid] = attcb[tid] + zb[0][tid]+zb[1][tid]+zb[2][tid]+zb[3][tid];
        __syncthreads();
        for (int s = wv*5; s < wv*5+5; ++s){
            float c0=covs[s], c1v=covs[s+1], c2v=covs[s+2];
            float p = 0.f;
            #pragma unroll
            for (int i=0;i<4;i++){
                int hh = lane + i*64;
                float e = b2f(encpL[s*256+hh]) + dps[hh]
                        + m30[i]*c0 + m31[i]*c1v + m32[i]*c2v;
                p += va[i]*ftanh(e);
            }
            #pragma unroll
            for (int off=32;off;off>>=1) p += __shfl_down(p, off);
            if (lane == 0) scs[s] = p;
        }
        __syncthreads();
        if (tid < 64){
            float a = scs[tid];
            float bsc = (tid < 16) ? scs[tid+64] : -3.4e38f;
            float mx = fmaxf(a, bsc);
            #pragma unroll
            for (int off=32;off;off>>=1) mx = fmaxf(mx, __shfl_xor(mx, off));
            float ea = __expf(a - mx);
            float eb = (tid < 16) ? __expf(bsc - mx) : 0.f;
            float sum = ea + eb;
            #pragma unroll
            for (int off=32;off;off>>=1) sum += __shfl_xor(sum, off);
            float inv = 1.f/sum;
            attns[tid] = ea*inv;
            if (tid < 16) attns[tid+64] = eb*inv;
        }
        __syncthreads();
        if (tid < 80) covs[tid+1] += attns[tid];
        {   // ctx partials (s-split 4)
            float acc = 0.f;
            for (int s=q*20; s<q*20+20; ++s)
                acc += attns[s]*b2f(encoL[s*256 + h]);
            zb[q][h] = acc;
        }
        __syncthreads();
        if (tid < 256)
            ctxb[h] = (unsigned short)f2b(zb[0][h]+zb[1][h]+zb[2][h]+zb[3][h]);
        float ep0=0.f,ep1=0.f,ep2=0.f,ep3=0.f;
        if (tid < 256){
            const float* er = embproj + ((size_t)b*TT + t)*1024;
            ep0=er[h]; ep1=er[h+256]; ep2=er[h+512]; ep3=er[h+768];
        }
        __syncthreads();
        // ---- lstm0: x = ctx (wx0), h = h1 (whh0) ----
        dot_phase<64>(m1 ? whh0 : wx0, m1 ? h1u : cxu, ks1*64, jq, &zb[m1*2+ks1][0]);
        __syncthreads();
        if (tid < 256){
            float i_ = ep0+zb[0][h]+zb[1][h]+zb[2][h]+zb[3][h];
            float f_ = ep1+zb[0][h+256]+zb[1][h+256]+zb[2][h+256]+zb[3][h+256];
            float g_ = ep2+zb[0][h+512]+zb[1][h+512]+zb[2][h+512]+zb[3][h+512];
            float o_ = ep3+zb[0][h+768]+zb[1][h+768]+zb[2][h+768]+zb[3][h+768];
            float cn = fsig(f_)*c1s[h] + fsig(i_)*ftanh(g_);
            c1s[h] = cn;
            h1b[h] = (unsigned short)f2b(fsig(o_)*ftanh(cn));
        }
        __syncthreads();
        // ---- lstm1: x = h1 (wih1), h = h2 (whh1) ----
        dot_phase<64>(m1 ? whh1 : wih1, m1 ? h2u : h1u, ks1*64, jq, &zb[m1*2+ks1][0]);
        __syncthreads();
        float hn = 0.f;
        if (tid < 256){
            float i_ = bz0+zb[0][h]+zb[1][h]+zb[2][h]+zb[3][h];
            float f_ = bz1+zb[0][h+256]+zb[1][h+256]+zb[2][h+256]+zb[3][h+256];
            float g_ = bz2+zb[0][h+512]+zb[1][h+512]+zb[2][h+512]+zb[3][h+512];
            float o_ = bz3+zb[0][h+768]+zb[1][h+768]+zb[2][h+768]+zb[3][h+768];
            float cn = fsig(f_)*c2s[h] + fsig(i_)*ftanh(g_);
            c2s[h] = cn;
            hn = fsig(o_)*ftanh(cn);
            h2b[h] = (unsigned short)f2b(hn);
        }
        // fused LayerNorm over h2
        float s1 = hn;
        #pragma unroll
        for (int off=32;off;off>>=1) s1 += __shfl_xor(s1, off);
        if (lane == 0) red[wv] = s1;
        __syncthreads();
        float mean = (red[0]+red[1]+red[2]+red[3]) * (1.f/256.f);
        __syncthreads();
        float d = (tid < 256) ? (hn - mean) : 0.f;
        float s2 = d*d;
        #pragma unroll
        for (int off=32;off;off>>=1) s2 += __shfl_xor(s2, off);
        if (lane == 0) red[wv] = s2;
        __syncthreads();
        float var = (red[0]+red[1]+red[2]+red[3]) * (1.f/256.f);
        if (tid < 256)
            normedb[((size_t)b*TT + t)*256 + h] =
                (unsigned short)f2b(d*rsqrtf(var + 1e-5f)*gg + bb2);
        __syncthreads();
    }
}

// ---------------------------------------------------------------------------
// Logits: bf16 MFMA, W-stationary. Block = 64 n-cols; loops all 80 m-tiles.
// ---------------------------------------------------------------------------
__global__ __launch_bounds__(256) void logits_mfma(
    const short* __restrict__ A, const short* __restrict__ Bw,
    const float* __restrict__ bias, float* __restrict__ out)
{
    int w = threadIdx.x >> 6, lane = threadIdx.x & 63;
    int n0 = blockIdx.x*64 + w*16;
    int row = lane & 15, kg = lane >> 4;
    bf16x8 bfr[8];
    const short* brow = Bw + (size_t)(n0 + row)*256 + kg*8;
    #pragma unroll
    for (int kk=0;kk<8;kk++) bfr[kk] = *reinterpret_cast<const bf16x8*>(brow + kk*32);
    float bv = bias[n0 + row];
    for (int mt=0; mt<80; ++mt){
        int m0 = mt*16;
        const short* arow = A + (size_t)(m0 + row)*256 + kg*8;
        f32x4 acc = {};
        #pragma unroll
        for (int kk=0;kk<8;kk++){
            bf16x8 a = *reinterpret_cast<const bf16x8*>(arow + kk*32);
            acc = __builtin_amdgcn_mfma_f32_16x16x32_bf16(a, bfr[kk], acc, 0, 0, 0);
        }
        #pragma unroll
        for (int r=0;r<4;r++){
            int m = m0 + kg*4 + r;
            out[(size_t)m*VV + n0 + row] = acc[r] + bv;
        }
    }
}

// ---------------------------------------------------------------------------
extern "C" void kernel_launch(void* const* d_in, const int* in_sizes, int n_in,
                              void* d_out, int out_size, void* d_ws, size_t ws_size,
                              hipStream_t stream)
{
    const float* video  = (const float*)d_in[0];
    const int*   caps   = (const int*)  d_in[1];
    const float* W_vp   = (const float*)d_in[2];
    const float* b_vp   = (const float*)d_in[3];
    const float* eWih0  = (const float*)d_in[4];
    const float* eWhh0  = (const float*)d_in[5];
    const float* e_bih0 = (const float*)d_in[6];
    const float* e_bhh0 = (const float*)d_in[7];
    const float* eWih1  = (const float*)d_in[8];
    const float* eWhh1  = (const float*)d_in[9];
    const float* e_bih1 = (const float*)d_in[10];
    const float* e_bhh1 = (const float*)d_in[11];
    const float* emb    = (const float*)d_in[12];
    const float* dWih0  = (const float*)d_in[13];
    const float* dWhh0  = (const float*)d_in[14];
    const float* d_bih0 = (const float*)d_in[15];
    const float* d_bhh0 = (const float*)d_in[16];
    const float* dWih1  = (const float*)d_in[17];
    const float* dWhh1  = (const float*)d_in[18];
    const float* d_bih1 = (const float*)d_in[19];
    const float* d_bhh1 = (const float*)d_in[20];
    const float* attWh  = (const float*)d_in[21];
    const float* attWs  = (const float*)d_in[22];
    const float* att_v  = (const float*)d_in[23];
    const float* attWc  = (const float*)d_in[24];
    const float* cov_w  = (const float*)d_in[25];
    const float* cov_b  = (const float*)d_in[26];
    const float* ln_g   = (const float*)d_in[27];
    const float* ln_b   = (const float*)d_in[28];
    const float* W_out  = (const float*)d_in[29];
    const float* b_out  = (const float*)d_in[30];
    float* out = (float*)d_out;

    float* W = (float*)d_ws;
    size_t o = 0;
    auto alloc = [&](size_t n){ size_t r = o; o += ((n + 63)/64)*64; return r; };

    // big shared region R: vp_part (8 x 5120x256) overlaps {zx0, embproj}
    float* R       = W + alloc((size_t)8*SS*BB*HH);     // 10,485,760 floats
    float* vp_part = R;
    float* zx0     = R;                                  // [(b*80+t)*1024]
    float* embproj = R + (size_t)SS*BB*1024;             // [(b*20+t)*1024]
    float* vp      = W + alloc((size_t)SS*BB*HH);        // [b*80+t][256]
    float* z1x     = W + alloc((size_t)SS*BB*1024);      // [(b*80+t)*1024]
    unsigned short* encpb = (unsigned short*)(W + alloc((size_t)BB*SS*HH/2));
    unsigned short* normedb = (unsigned short*)(W + alloc((size_t)BB*TT*HH/2));
    unsigned short* h1seq = (unsigned short*)(W + alloc((size_t)SS*BB*HH/2));
    unsigned short* h2seq = (unsigned short*)(W + alloc((size_t)SS*BB*HH/2));
    float* encfC   = W + alloc(BB*512);
    unsigned short* encfH = (unsigned short*)(W + alloc(BB*256));
    unsigned* pkWhh0e = (unsigned*)(W + alloc(128*1024));
    unsigned* pkWih1e = (unsigned*)(W + alloc(128*1024));
    unsigned* pkWhh1e = (unsigned*)(W + alloc(128*1024));
    unsigned* pkWx0d  = (unsigned*)(W + alloc(128*1024));
    unsigned* pkWhh0d = (unsigned*)(W + alloc(128*1024));
    unsigned* pkWih1d = (unsigned*)(W + alloc(128*1024));
    unsigned* pkWhh1d = (unsigned*)(W + alloc(128*1024));
    unsigned* pkWs    = (unsigned*)(W + alloc(128*256));
    float* M3      = W + alloc(768);
    float* attcb   = W + alloc(256);
    float* b0e     = W + alloc(1024);
    float* b1e     = W + alloc(1024);
    float* b0d     = W + alloc(1024);
    float* b1d     = W + alloc(1024);
    unsigned short* Wob  = (unsigned short*)(W + alloc((size_t)VV*HH/2));
    unsigned short* Wib1 = (unsigned short*)(W + alloc(1024*HH/2));
    unsigned short* Whb  = (unsigned short*)(W + alloc(256*HH/2));
    (void)ws_size; (void)n_in; (void)in_sizes; (void)out_size;

    prep_kernel<<<6018, 256, 0, stream>>>(
        eWhh0, eWih1, eWhh1, dWih0, dWhh0, dWih1, dWhh1, attWs, attWc,
        cov_w, cov_b, e_bih0, e_bhh0, e_bih1, e_bhh1, d_bih0, d_bhh0, d_bih1, d_bhh1,
        W_out, attWh,
        pkWhh0e, pkWih1e, pkWhh1e, pkWx0d, pkWhh0d, pkWih1d, pkWhh1d, pkWs,
        M3, attcb, b0e, b1e, b0d, b1d, Wob, Wib1, Whb);

    // vp = video @ W_vp^T + b_vp  (5120x256, K=4096) split-K x8
    gemm_nt<64,64,4,4><<<dim3(4,80,8), 256, 0, stream>>>(
        SS*BB, HH, FF, video, FF, W_vp, FF, vp_part, HH, b_vp, nullptr,
        512, (size_t)SS*BB*HH);
    vp_reduce<<<1280, 256, 0, stream>>>(vp_part, vp);

    // zx0[b*80+t] = vp @ eWih0^T + (bih0+bhh0)   (5120x1024, K=256)
    gemm_nt<64,64,4,4><<<dim3(16,80), 256, 0, stream>>>(
        SS*BB, 1024, HH, vp, HH, eWih0, HH, zx0, 1024, b0e, nullptr, HH, 0);

    // embproj[b*20+t] = emb[cap] @ dWih0[:, :256]^T + (bih0+bhh0)  (1280x1024, K=256)
    gemm_nt<64,64,4,4><<<dim3(16,20), 256, 0, stream>>>(
        TT*BB, 1024, HH, emb, HH, dWih0, 512, embproj, 1024, b0d, caps, HH, 0);

    // encoder layer0 scan (weight-resident)
    lstm_scan<<<64, 512, 0, stream>>>(SS, zx0, pkWhh0e, h1seq, nullptr,
                                      encfH, encfC, 0);

    // z1x = h1seq @ Wih1^T + b1e  (5120x1024, K=256, bf16 MFMA)
    z1x_mfma<<<dim3(16, 80), 256, 0, stream>>>(
        (const short*)h1seq, (const short*)Wib1, b1e, z1x);

    // encoder layer1 scan (weight-resident); h2seq bf16 doubles as enco
    lstm_scan<<<64, 512, 0, stream>>>(SS, z1x, pkWhh1e, h2seq, nullptr,
                                      encfH, encfC, 256);

    // encp = h2seq @ attWh^T  (5120x256, K=256, bf16 MFMA, bf16 out)
    encp_mfma<<<dim3(4, 80), 256, 0, stream>>>(
        (const short*)h2seq, (const short*)Whb, encpb);

    // decoder scan: 64 per-batch blocks (attn + lstm0 + lstm1 + LN fused)
    dec_scan<<<64, 1024, 0, stream>>>(embproj, pkWx0d, pkWhh0d, pkWih1d, pkWhh1d,
                                      pkWs, b1d, encpb, h2seq, att_v, M3, attcb,
                                      ln_g, ln_b, encfC, encfH, normedb);

    // logits = normed @ W_out^T + b_out  (1280 x 32000, K=256)
    logits_mfma<<<VV/64, 256, 0, stream>>>(
        (const short*)normedb, (const short*)Wob, b_out, out);
}